// Round 12
// baseline (132.713 us; speedup 1.0000x reference)
//
#include <hip/hip_runtime.h>

typedef unsigned int u32;
typedef unsigned short u16;
typedef __attribute__((ext_vector_type(4))) float f32x4;
typedef __attribute__((ext_vector_type(8))) short s16x8;

#define S_LEN 2048
#define DMODEL 2048
#define NH 16
#define NKV 4
#define HD 128
#define WIN 512
// 0.125 (1/sqrt(64)) * log2(e): folds score scale + exp2-domain conversion into Q
#define QSCALE 0.18033688011112042f

#define WAIT_VMCNT4 asm volatile("s_waitcnt vmcnt(4)" ::: "memory")
#define WAIT_VMCNT0 asm volatile("s_waitcnt vmcnt(0)" ::: "memory")

__device__ __forceinline__ u16 f2bf(float f) {
  union { float f; u32 u; } v; v.f = f;
  u32 r = v.u + 0x7FFFu + ((v.u >> 16) & 1u);
  return (u16)(r >> 16);
}
__device__ __forceinline__ float bf2f(u16 h) {
  union { u32 u; float f; } v; v.u = ((u32)h) << 16;
  return v.f;
}

__device__ __forceinline__ void async16(const void* g, void* l) {
  __builtin_amdgcn_global_load_lds((const __attribute__((address_space(1))) void*)g,
                                   (__attribute__((address_space(3))) void*)l, 16, 0, 0);
}

// ---------------- prep kernel ----------------
// bid < 4096: x f32->bf16 convert. 4096..14336: weight transposes
// (Wq 4096 | Wk 1024 | Wv 1024 | Wo 4096). >=14336: rope cos/sin table.
__global__ __launch_bounds__(256) void k_prep(const float* __restrict__ x, u16* __restrict__ xb,
                                              const float* __restrict__ Wq,
                                              const float* __restrict__ Wk,
                                              const float* __restrict__ Wv,
                                              const float* __restrict__ Wo,
                                              u16* __restrict__ WT, u16* __restrict__ WoT,
                                              float2* __restrict__ cs) {
  __shared__ float tile[32][33];
  const int bid = blockIdx.x;
  if (bid >= 14336) {  // rope table: 512 blocks x 4 s-rows x 64 d
    int s = (bid - 14336) * 4 + (threadIdx.x >> 6);
    int d = threadIdx.x & 63;
    float invf = expf(-((float)(2 * d) / (float)HD) * logf(10000.0f));
    float fr = (float)s * invf;
    float sv, cv;
    sincosf(fr, &sv, &cv);
    cs[s * 64 + d] = make_float2(cv, sv);
    return;
  }
  if (bid < 4096) {
    int i = bid * 256 + threadIdx.x;
    float4 v = ((const float4*)x)[i];
    ushort4 o;
    o.x = f2bf(v.x); o.y = f2bf(v.y); o.z = f2bf(v.z); o.w = f2bf(v.w);
    ((ushort4*)xb)[i] = o;
    return;
  }
  const int b = bid - 4096;
  const float* src;
  u16* dst;
  int N, nt, kt;
  if (b < 4096) {
    src = Wq; dst = WT; N = 2048; nt = b & 63; kt = b >> 6;
  } else if (b < 5120) {
    int i = b - 4096;
    src = Wk; dst = WT + (size_t)2048 * 2048; N = 512; nt = i & 15; kt = i >> 4;
  } else if (b < 6144) {
    int i = b - 5120;
    src = Wv; dst = WT + (size_t)2560 * 2048; N = 512; nt = i & 15; kt = i >> 4;
  } else {
    int i = b - 6144;
    src = Wo; dst = WoT; N = 2048; nt = i & 63; kt = i >> 6;
  }
  const int tx = threadIdx.x & 31, ty = threadIdx.x >> 5;
  const int n0 = nt * 32, k0 = kt * 32;
#pragma unroll
  for (int i = 0; i < 4; ++i)
    tile[ty + 8 * i][tx] = src[(size_t)(k0 + ty + 8 * i) * N + n0 + tx];
  __syncthreads();
#pragma unroll
  for (int i = 0; i < 4; ++i)
    dst[(size_t)(n0 + ty + 8 * i) * 2048 + k0 + tx] = f2bf(tile[tx][ty + 8 * i]);
}

// rope in-place on kr only (Q-rope fused into k_attn). grid exact: 2048 blocks.
__global__ void k_rope_k(u16* __restrict__ kr, const float2* __restrict__ cs) {
  int i = blockIdx.x * blockDim.x + threadIdx.x;
  int rowg = i >> 6, d = i & 63;
  int s = rowg & (S_LEN - 1);
  float2 c = cs[s * 64 + d];
  u16* p = kr + (size_t)rowg * HD;
  float a = bf2f(p[d]), b = bf2f(p[d + 64]);
  p[d]      = f2bf(a * c.x - b * c.y);
  p[d + 64] = f2bf(b * c.x + a * c.y);
}

// ---------------- GEMM (R9 version: BK=64, 2-buf T3-min, 3 blocks/CU) ----------------
// A [M][K] bf16 row-major, BT [N][K] bf16. 64x128 tile, BK=64, 4 waves (2x2 of
// 32x64), double-buffered LDS (T3-min), chunked XCD swizzle.
// MODE 0: scatter epilogue -> qr[h][s][d], kr[h][s][d], vt[h][d][s]
// MODE 1: plain fp32 C[M][N]

template <int MODE>
__global__ __launch_bounds__(256) void k_gemm(const u16* __restrict__ A, const u16* __restrict__ BT,
                                              float* __restrict__ Cf, int K, int N,
                                              u16* __restrict__ qr, u16* __restrict__ kr,
                                              u16* __restrict__ vt) {
  // A rows 0..63, B rows 64..191; each row 64 u16 = 128B; 24KB per buffer
  __shared__ u16 S[2][192 * 64];
  const int t = threadIdx.x;
  const int l = t & 63, w = t >> 6;
  const int lg = l >> 4, ll = l & 15;

  // chunked XCD swizzle (bijective: nwg % 8 == 0 for both call sites)
  const u32 nwg = gridDim.x * gridDim.y;
  const u32 bid = blockIdx.y * gridDim.x + blockIdx.x;  // m-fastest linearization
  const u32 sid = (bid & 7u) * (nwg >> 3) + (bid >> 3);
  const int m0 = (int)(sid % gridDim.x) * 64;
  const int n0 = (int)(sid / gridDim.x) * 128;

  const int wm = (w >> 1) * 32, wn = (w & 1) * 64;

  const u16* gp[6];
  u32 lo[6];
#pragma unroll
  for (int j = 0; j < 6; ++j) {
    u32 u = (u32)t * 16u + (u32)j * 4096u;
    u32 row = u >> 7;
    u32 slot = ((u >> 4) & 7u) ^ (row & 7u);
    lo[j] = u;
    gp[j] = (row < 64 ? A + (size_t)(m0 + (int)row) * K
                      : BT + (size_t)(n0 + (int)(row - 64)) * K) + slot * 8;
  }
  auto stage = [&](int b, int k0) {
#pragma unroll
    for (int j = 0; j < 6; ++j) async16(gp[j] + k0, (char*)S[b] + lo[j]);
  };

  f32x4 acc[2][4];
#pragma unroll
  for (int i = 0; i < 2; ++i)
#pragma unroll
    for (int j = 0; j < 4; ++j) acc[i][j] = (f32x4){0.f, 0.f, 0.f, 0.f};

  stage(0, 0);
  __syncthreads();

  const int nit = K / 64;
#pragma unroll 2
  for (int it = 0; it < nit; ++it) {
    const int cur = it & 1;
    if (it + 1 < nit) stage(cur ^ 1, (it + 1) * 64);  // loads fly under compute

    s16x8 af[2][2], bq[4][2];
#pragma unroll
    for (int mt = 0; mt < 2; ++mt) {
      u32 r = (u32)(wm + mt * 16 + ll);
#pragma unroll
      for (int ks = 0; ks < 2; ++ks)
        af[mt][ks] = *(const s16x8*)((const char*)S[cur] + r * 128u +
                                     ((((u32)(ks * 4 + lg)) ^ (r & 7u)) * 16u));
    }
#pragma unroll
    for (int nt = 0; nt < 4; ++nt) {
      u32 r = (u32)(64 + wn + nt * 16 + ll);
#pragma unroll
      for (int ks = 0; ks < 2; ++ks)
        bq[nt][ks] = *(const s16x8*)((const char*)S[cur] + r * 128u +
                                     ((((u32)(ks * 4 + lg)) ^ (r & 7u)) * 16u));
    }
#pragma unroll
    for (int ks = 0; ks < 2; ++ks)
#pragma unroll
      for (int mt = 0; mt < 2; ++mt)
#pragma unroll
        for (int nt = 0; nt < 4; ++nt)
          acc[mt][nt] = __builtin_amdgcn_mfma_f32_16x16x32_bf16(af[mt][ks], bq[nt][ks],
                                                                acc[mt][nt], 0, 0, 0);
    __syncthreads();
  }

  if (MODE == 1) {
#pragma unroll
    for (int mt = 0; mt < 2; ++mt) {
      int srow = m0 + wm + mt * 16 + lg * 4;
#pragma unroll
      for (int nt = 0; nt < 4; ++nt) {
        int col = n0 + wn + nt * 16 + ll;
        f32x4 a = acc[mt][nt];
#pragma unroll
        for (int j = 0; j < 4; ++j) Cf[(size_t)(srow + j) * N + col] = a[j];
      }
    }
  } else {
#pragma unroll
    for (int nt = 0; nt < 4; ++nt) {
      int cb = n0 + wn + nt * 16;  // wave-uniform
#pragma unroll
      for (int mt = 0; mt < 2; ++mt) {
        int srow = m0 + wm + mt * 16 + lg * 4;
        f32x4 a = acc[mt][nt];
        if (cb < 2048) {
          int hh = cb >> 7, d = (cb & 127) + ll;
          u16* p = qr + ((size_t)hh * S_LEN) * HD + d;
#pragma unroll
          for (int j = 0; j < 4; ++j) p[(size_t)(srow + j) * HD] = f2bf(a[j]);
        } else if (cb < 2560) {
          int hh = (cb - 2048) >> 7, d = ((cb - 2048) & 127) + ll;
          u16* p = kr + ((size_t)hh * S_LEN) * HD + d;
#pragma unroll
          for (int j = 0; j < 4; ++j) p[(size_t)(srow + j) * HD] = f2bf(a[j]);
        } else {
          int hh = (cb - 2560) >> 7, d = ((cb - 2560) & 127) + ll;
          ushort4 pk;
          pk.x = f2bf(a[0]); pk.y = f2bf(a[1]); pk.z = f2bf(a[2]); pk.w = f2bf(a[3]);
          *(ushort4*)(vt + ((size_t)hh * HD + d) * S_LEN + srow) = pk;
        }
      }
    }
  }
}

// ---------------- attention ----------------
// Head-sharing grid (S/16, NKV), wave w = head hkv*4+w; all waves share one
// key window. Both passes: 64-key chunks, 3-buffer (16KB) K staging, counted
// vmcnt(4) + raw s_barrier, 2-ahead (stage after barrier; buf distance 2
// race-free). Pass 2 reads V fragments DIRECTLY from global (vt is
// L2-resident; 16x64B semi-coalesced) issued right after the barrier so
// ~600cy of QK^T/exp/P-pack hides the L2 latency -> V LDS traffic gone
// (LDS was the bottleneck pipe: ~20us of ds-op occupancy at R9).
// Issue order per iter keeps vmcnt exact: V-loads(tc) BEFORE stage(tc+2),
// so compiler's vmcnt(4) waits for V while leaving stage(tc+2) in flight,
// and WAIT_VMCNT4 at iter top leaves only stage(tc+1) outstanding.
// Q-RoPE (+QSCALE exp2-domain fold) in-register. No-max exp2 softmax.
__global__ __launch_bounds__(256, 2) void k_attn(const u16* __restrict__ qr,
                                                 const u16* __restrict__ kr,
                                                 const u16* __restrict__ vt,
                                                 const float* __restrict__ lam,
                                                 const float2* __restrict__ cs,
                                                 u16* __restrict__ ao) {
  __shared__ u16 KV[3][8192];   // 3 x 16KB K tiles (64 rows x 256B)
  __shared__ u16 P[4][16 * 72]; // per-wave P^T tile (16 q x 64 keys), stride 72 u16
  const int t = threadIdx.x;
  const int l = t & 63, w = t >> 6;
  const int lg = l >> 4, ll = l & 15;
  const int hkv = blockIdx.y;
  const int h = hkv * 4 + w;
  const int qs = blockIdx.x * 16;
  const int row = qs + ll;

  const u16* Qp = qr + ((size_t)h * S_LEN + qs) * HD;
  const u16* Kp = kr + (size_t)hkv * S_LEN * HD;
  const u16* Vp = vt + (size_t)hkv * HD * S_LEN;

  const int kbeg = (qs >= 512) ? ((qs - 511) & ~63) : 0;
  const int nch = (qs + 15 - kbeg) / 64 + 1;  // 64-key chunks, both passes

  // K staging coords (16KB tile: 64 rows x 256B, 16 slots, slot ^= row&7)
  u32 ku1[4], kr1[4], ks1[4];
#pragma unroll
  for (int j = 0; j < 4; ++j) {
    u32 u = (u32)t * 16u + (u32)j * 4096u;
    ku1[j] = u;
    kr1[j] = u >> 8;
    ks1[j] = ((u >> 4) & 15u) ^ (kr1[j] & 7u);
  }
  auto stageK = [&](int buf, int tcc) {
    const int c = kbeg + tcc * 64;
    char* dst = (char*)KV + (size_t)buf * 16384;
#pragma unroll
    for (int j = 0; j < 4; ++j)
      async16(Kp + (size_t)(c + kr1[j]) * HD + ks1[j] * 8, dst + ku1[j]);
  };

  // ---- Q fragments + in-register RoPE (+QSCALE) ----
  s16x8 qa[4];
#pragma unroll
  for (int i = 0; i < 4; ++i)
    qa[i] = *(const s16x8*)(Qp + (size_t)ll * HD + i * 32 + lg * 8);
  {
    const float4* cp4 = (const float4*)(cs + (size_t)row * 64);  // 32 float4/row
#pragma unroll
    for (int i = 0; i < 2; ++i) {
      float4 cv[4];
#pragma unroll
      for (int jj = 0; jj < 4; ++jj) cv[jj] = cp4[i * 16 + lg * 4 + jj];
      s16x8 lo = qa[i], hi = qa[i + 2];
#pragma unroll
      for (int j = 0; j < 8; ++j) {
        float cc = (j & 1) ? cv[j >> 1].z : cv[j >> 1].x;
        float ss = (j & 1) ? cv[j >> 1].w : cv[j >> 1].y;
        float a = bf2f((u16)lo[j]), b = bf2f((u16)hi[j]);
        lo[j] = (short)f2bf((a * cc - b * ss) * QSCALE);
        hi[j] = (short)f2bf((b * cc + a * ss) * QSCALE);
      }
      qa[i] = lo; qa[i + 2] = hi;
    }
  }

  const f32x4 zero = {0.f, 0.f, 0.f, 0.f};
  float z1 = 0.f, z2 = 0.f;

  // ---- pass 1: Z sums (3-buf K, counted vmcnt, 2-ahead) ----
  stageK(0, 0);
  stageK(1, (nch > 1) ? 1 : 0);

  for (int tc = 0; tc < nch; ++tc) {
    WAIT_VMCNT4;                    // own stage tc landed (in-order vmcnt retire)
    __builtin_amdgcn_s_barrier();   // all waves' stage tc landed
    {
      int ci = tc + 2; if (ci > nch - 1) ci = nch - 1;  // clamped, uniform
      stageK((tc + 2) % 3, ci);
    }
    const int c = kbeg + tc * 64;
    const u16* Kb = (const u16*)((const char*)KV + (size_t)(tc % 3) * 16384);
    float acc1 = 0.f, acc2 = 0.f;
#pragma unroll
    for (int kt = 0; kt < 4; ++kt) {
      const int kbase = c + kt * 16;
      if (kbase > qs + 15 || kbase + 15 < qs - (WIN - 1)) continue;  // uniform
      const int kr_ = kt * 16 + ll;
      const u16* kp = Kb + kr_ * 128;
      const u32 sw = (u32)(kr_ & 7);
      s16x8 b0 = *(const s16x8*)(kp + ((lg ^ sw) * 8));
      s16x8 b1 = *(const s16x8*)(kp + (((4 + lg) ^ sw) * 8));
      s16x8 b2 = *(const s16x8*)(kp + (((8 + lg) ^ sw) * 8));
      s16x8 b3 = *(const s16x8*)(kp + (((12 + lg) ^ sw) * 8));
      f32x4 a = __builtin_amdgcn_mfma_f32_16x16x32_bf16(b0, qa[0], zero, 0, 0, 0);
      a = __builtin_amdgcn_mfma_f32_16x16x32_bf16(b1, qa[1], a, 0, 0, 0);
      f32x4 b = __builtin_amdgcn_mfma_f32_16x16x32_bf16(b2, qa[2], zero, 0, 0, 0);
      b = __builtin_amdgcn_mfma_f32_16x16x32_bf16(b3, qa[3], b, 0, 0, 0);
      const bool fullk = (kbase + 15 <= qs) && (kbase >= qs - 496);
      if (!fullk) {
#pragma unroll
        for (int j = 0; j < 4; ++j) {
          int key = kbase + lg * 4 + j;
          bool ok = (key <= row) && (key > row - WIN);
          a[j] = ok ? a[j] : -1e30f;
          b[j] = ok ? b[j] : -1e30f;
        }
      }
#pragma unroll
      for (int j = 0; j < 4; ++j) {
        acc1 += __builtin_amdgcn_exp2f(a[j]);  // exp2(-1e30) flushes to 0
        acc2 += __builtin_amdgcn_exp2f(b[j]);
      }
    }
    z1 += acc1; z2 += acc2;
  }

  // merge the 4 lg-group partials (lanes ll, ll+16, ll+32, ll+48 share q=ll)
  z1 += __shfl_xor(z1, 16, 64); z1 += __shfl_xor(z1, 32, 64);
  z2 += __shfl_xor(z2, 16, 64); z2 += __shfl_xor(z2, 32, 64);
  const float l2z1 = __builtin_amdgcn_logf(z1);  // v_log_f32 = log2
  const float l2z2 = __builtin_amdgcn_logf(z2);
  const float lm = lam[h];

  // ---- pass 2: diff-combine + PV (K staged 64-key, V direct-from-global) ----
  f32x4 o[8];
#pragma unroll
  for (int dt = 0; dt < 8; ++dt) o[dt] = zero;
  float dsum = 0.f;
  u16* Pw = &P[w][0];

  WAIT_VMCNT0;      // pass-1 trailing stages landed
  __syncthreads();  // all waves done with pass-1 buffers

  stageK(0, 0);
  stageK(1, (nch > 1) ? 1 : 0);

  for (int tc = 0; tc < nch; ++tc) {
    WAIT_VMCNT4;                    // own stage tc landed
    __builtin_amdgcn_s_barrier();   // all waves' stage tc landed
    const int c = kbeg + tc * 64;

    // V fragments: direct global loads, issued EARLY (before stage(tc+2), so
    // the compiler's vmcnt wait before their use leaves stage(tc+2) in flight)
    s16x8 vf[8][2];
#pragma unroll
    for (int dt = 0; dt < 8; ++dt) {
      const u16* vp = Vp + (size_t)(dt * 16 + ll) * S_LEN + c + lg * 8;
      vf[dt][0] = *(const s16x8*)(vp);
      vf[dt][1] = *(const s16x8*)(vp + 32);
    }
    {
      int ci = tc + 2; if (ci > nch - 1) ci = nch - 1;  // clamped, uniform
      stageK((tc + 2) % 3, ci);
    }

    const u16* Kb = (const u16*)((const char*)KV + (size_t)(tc % 3) * 16384);
    __builtin_amdgcn_s_setprio(1);
#pragma unroll
    for (int kt = 0; kt < 4; ++kt) {
      const int kbase = c + kt * 16;
      if (kbase > qs + 15 || kbase + 15 < qs - (WIN - 1)) {  // uniform skip
        ushort4 zz; zz.x = zz.y = zz.z = zz.w = 0;
        *(ushort4*)(&Pw[ll * 72 + kt * 16 + lg * 4]) = zz;
        continue;
      }
      const int kr_ = kt * 16 + ll;
      const u16* kp = Kb + kr_ * 128;
      const u32 sw = (u32)(kr_ & 7);
      s16x8 b0 = *(const s16x8*)(kp + ((lg ^ sw) * 8));
      s16x8 b1 = *(const s16x8*)(kp + (((4 + lg) ^ sw) * 8));
      s16x8 b2 = *(const s16x8*)(kp + (((8 + lg) ^ sw) * 8));
      s16x8 b3 = *(const s16x8*)(kp + (((12 + lg) ^ sw) * 8));
      f32x4 a = __builtin_amdgcn_mfma_f32_16x16x32_bf16(b0, qa[0], zero, 0, 0, 0);
      a = __builtin_amdgcn_mfma_f32_16x16x32_bf16(b1, qa[1], a, 0, 0, 0);
      f32x4 b = __builtin_amdgcn_mfma_f32_16x16x32_bf16(b2, qa[2], zero, 0, 0, 0);
      b = __builtin_amdgcn_mfma_f32_16x16x32_bf16(b3, qa[3], b, 0, 0, 0);
      const bool fullk = (kbase + 15 <= qs) && (kbase >= qs - 496);
      if (!fullk) {
#pragma unroll
        for (int j = 0; j < 4; ++j) {
          int key = kbase + lg * 4 + j;
          bool ok = (key <= row) && (key > row - WIN);
          a[j] = ok ? a[j] : -1e30f;
          b[j] = ok ? b[j] : -1e30f;
        }
      }
      float d4[4];
#pragma unroll
      for (int j = 0; j < 4; ++j) {
        float a1 = __builtin_amdgcn_exp2f(a[j] - l2z1);
        float a2 = __builtin_amdgcn_exp2f(b[j] - l2z2);
        float d = fmaxf(fmaf(-lm, a2, a1), 0.f);
        d4[j] = d;
        dsum += d;
      }
      u32 p01, p23;
      asm("v_cvt_pk_bf16_f32 %0, %1, %2" : "=v"(p01) : "v"(d4[0]), "v"(d4[1]));
      asm("v_cvt_pk_bf16_f32 %0, %1, %2" : "=v"(p23) : "v"(d4[2]), "v"(d4[3]));
      uint2 pk; pk.x = p01; pk.y = p23;
      *(uint2*)(&Pw[ll * 72 + kt * 16 + lg * 4]) = pk;
    }
    // per-wave LDS transpose round-trip (wave-synchronous; compiler waits lgkm)
    s16x8 pf0 = *(const s16x8*)(&Pw[ll * 72 + lg * 8]);
    s16x8 pf1 = *(const s16x8*)(&Pw[ll * 72 + 32 + lg * 8]);
#pragma unroll
    for (int dt = 0; dt < 8; ++dt) {
      o[dt] = __builtin_amdgcn_mfma_f32_16x16x32_bf16(pf0, vf[dt][0], o[dt], 0, 0, 0);
      o[dt] = __builtin_amdgcn_mfma_f32_16x16x32_bf16(pf1, vf[dt][1], o[dt], 0, 0, 0);
    }
    __builtin_amdgcn_s_setprio(0);
  }
  WAIT_VMCNT0;  // drain trailing stages before kernel end

  // dsum: merge lg partials, then fetch 1/(sum+eps) for output rows lg*4+j
  dsum += __shfl_xor(dsum, 16, 64);
  dsum += __shfl_xor(dsum, 32, 64);
  const float rds = __builtin_amdgcn_rcpf(dsum + 1e-6f);
  float rdsj[4];
#pragma unroll
  for (int j = 0; j < 4; ++j) rdsj[j] = __shfl(rds, lg * 4 + j, 64);

#pragma unroll
  for (int dt = 0; dt < 8; ++dt) {
#pragma unroll
    for (int j = 0; j < 4; ++j) {
      int srow = qs + lg * 4 + j;
      ao[(size_t)srow * DMODEL + h * HD + dt * 16 + ll] = f2bf(o[dt][j] * rdsj[j]);
    }
  }
}

// ---------------- launch ----------------

extern "C" void kernel_launch(void* const* d_in, const int* in_sizes, int n_in,
                              void* d_out, int out_size, void* d_ws, size_t ws_size,
                              hipStream_t stream) {
  const float* x = (const float*)d_in[0];
  const float* Wq = (const float*)d_in[1];
  const float* Wk = (const float*)d_in[2];
  const float* Wv = (const float*)d_in[3];
  const float* Wo = (const float*)d_in[4];
  const float* lam = (const float*)d_in[5];
  float* out = (float*)d_out;

  char* ws = (char*)d_ws;
  u16* xb = (u16*)(ws);                               // 8 MB  [2048][2048]
  u16* WT = (u16*)(ws + (8u << 20));                  // 12 MB [3072][2048] (Wq^T|Wk^T|Wv^T)
  u16* WoT = (u16*)(ws + (20u << 20));                // 8 MB  [2048][2048]
  u16* qr = (u16*)(ws + (28u << 20));                 // 8 MB  [16][2048][128]
  u16* kr = (u16*)(ws + (36u << 20));                 // 2 MB  [4][2048][128]
  u16* vt = (u16*)(ws + (38u << 20));                 // 2 MB  [4][128][2048]
  u16* ao = (u16*)(ws + (40u << 20));                 // 8 MB  [2048][2048]
  float2* cs = (float2*)(ws + (48u << 20));           // 1 MB  [2048][64]

  k_prep<<<14848, 256, 0, stream>>>(x, xb, Wq, Wk, Wv, Wo, WT, WoT, cs);

  k_gemm<0><<<dim3(32, 24), 256, 0, stream>>>(xb, WT, nullptr, 2048, 3072, qr, kr, vt);

  // K roped in-place; Q-rope (+QSCALE, exp2-domain fold) fused into k_attn
  k_rope_k<<<(NKV * S_LEN * 64) / 256, 256, 0, stream>>>(kr, cs);

  k_attn<<<dim3(S_LEN / 16, NKV), 256, 0, stream>>>(qr, kr, vt, lam, cs, ao);

  k_gemm<1><<<dim3(32, 16), 256, 0, stream>>>(ao, WoT, out, 2048, 2048, nullptr, nullptr, nullptr);
}

// Round 13
// 115.291 us; speedup vs baseline: 1.1511x; 1.1511x over previous
//
#include <hip/hip_runtime.h>

typedef unsigned int u32;
typedef unsigned short u16;
typedef __attribute__((ext_vector_type(4))) float f32x4;
typedef __attribute__((ext_vector_type(8))) short s16x8;

#define S_LEN 2048
#define DMODEL 2048
#define NH 16
#define NKV 4
#define HD 128
#define WIN 512
// 0.125 (1/sqrt(64)) * log2(e): folds score scale + exp2-domain conversion into Q
#define QSCALE 0.18033688011112042f

#define WAIT_VMCNT4 asm volatile("s_waitcnt vmcnt(4)" ::: "memory")
#define WAIT_VMCNT0 asm volatile("s_waitcnt vmcnt(0)" ::: "memory")

__device__ __forceinline__ u16 f2bf(float f) {
  union { float f; u32 u; } v; v.f = f;
  u32 r = v.u + 0x7FFFu + ((v.u >> 16) & 1u);
  return (u16)(r >> 16);
}
__device__ __forceinline__ float bf2f(u16 h) {
  union { u32 u; float f; } v; v.u = ((u32)h) << 16;
  return v.f;
}

__device__ __forceinline__ void async16(const void* g, void* l) {
  __builtin_amdgcn_global_load_lds((const __attribute__((address_space(1))) void*)g,
                                   (__attribute__((address_space(3))) void*)l, 16, 0, 0);
}

// ---------------- prep kernel ----------------
// bid < 4096: x f32->bf16 convert. 4096..14336: weight transposes
// (Wq 4096 | Wk 1024 | Wv 1024 | Wo 4096). >=14336: rope cos/sin table.
__global__ __launch_bounds__(256) void k_prep(const float* __restrict__ x, u16* __restrict__ xb,
                                              const float* __restrict__ Wq,
                                              const float* __restrict__ Wk,
                                              const float* __restrict__ Wv,
                                              const float* __restrict__ Wo,
                                              u16* __restrict__ WT, u16* __restrict__ WoT,
                                              float2* __restrict__ cs) {
  __shared__ float tile[32][33];
  const int bid = blockIdx.x;
  if (bid >= 14336) {  // rope table: 512 blocks x 4 s-rows x 64 d
    int s = (bid - 14336) * 4 + (threadIdx.x >> 6);
    int d = threadIdx.x & 63;
    float invf = expf(-((float)(2 * d) / (float)HD) * logf(10000.0f));
    float fr = (float)s * invf;
    float sv, cv;
    sincosf(fr, &sv, &cv);
    cs[s * 64 + d] = make_float2(cv, sv);
    return;
  }
  if (bid < 4096) {
    int i = bid * 256 + threadIdx.x;
    float4 v = ((const float4*)x)[i];
    ushort4 o;
    o.x = f2bf(v.x); o.y = f2bf(v.y); o.z = f2bf(v.z); o.w = f2bf(v.w);
    ((ushort4*)xb)[i] = o;
    return;
  }
  const int b = bid - 4096;
  const float* src;
  u16* dst;
  int N, nt, kt;
  if (b < 4096) {
    src = Wq; dst = WT; N = 2048; nt = b & 63; kt = b >> 6;
  } else if (b < 5120) {
    int i = b - 4096;
    src = Wk; dst = WT + (size_t)2048 * 2048; N = 512; nt = i & 15; kt = i >> 4;
  } else if (b < 6144) {
    int i = b - 5120;
    src = Wv; dst = WT + (size_t)2560 * 2048; N = 512; nt = i & 15; kt = i >> 4;
  } else {
    int i = b - 6144;
    src = Wo; dst = WoT; N = 2048; nt = i & 63; kt = i >> 6;
  }
  const int tx = threadIdx.x & 31, ty = threadIdx.x >> 5;
  const int n0 = nt * 32, k0 = kt * 32;
#pragma unroll
  for (int i = 0; i < 4; ++i)
    tile[ty + 8 * i][tx] = src[(size_t)(k0 + ty + 8 * i) * N + n0 + tx];
  __syncthreads();
#pragma unroll
  for (int i = 0; i < 4; ++i)
    dst[(size_t)(n0 + ty + 8 * i) * 2048 + k0 + tx] = f2bf(tile[tx][ty + 8 * i]);
}

// rope in-place on kr only (Q-rope fused into k_attn). grid exact: 2048 blocks.
__global__ void k_rope_k(u16* __restrict__ kr, const float2* __restrict__ cs) {
  int i = blockIdx.x * blockDim.x + threadIdx.x;
  int rowg = i >> 6, d = i & 63;
  int s = rowg & (S_LEN - 1);
  float2 c = cs[s * 64 + d];
  u16* p = kr + (size_t)rowg * HD;
  float a = bf2f(p[d]), b = bf2f(p[d + 64]);
  p[d]      = f2bf(a * c.x - b * c.y);
  p[d + 64] = f2bf(b * c.x + a * c.y);
}

// ---------------- GEMM (BK=64, 2-buf T3-min, 3 blocks/CU) ----------------
// A [M][K] bf16 row-major, BT [N][K] bf16. 64x128 tile, BK=64, 4 waves (2x2 of
// 32x64), double-buffered LDS (T3-min), chunked XCD swizzle.
// MODE 0: scatter epilogue -> qr[h][s][d], kr[h][s][d], vt[h][d][s]
// MODE 1: plain fp32 C[M][N]

template <int MODE>
__global__ __launch_bounds__(256) void k_gemm(const u16* __restrict__ A, const u16* __restrict__ BT,
                                              float* __restrict__ Cf, int K, int N,
                                              u16* __restrict__ qr, u16* __restrict__ kr,
                                              u16* __restrict__ vt) {
  // A rows 0..63, B rows 64..191; each row 64 u16 = 128B; 24KB per buffer
  __shared__ u16 S[2][192 * 64];
  const int t = threadIdx.x;
  const int l = t & 63, w = t >> 6;
  const int lg = l >> 4, ll = l & 15;

  // chunked XCD swizzle (bijective: nwg % 8 == 0 for both call sites)
  const u32 nwg = gridDim.x * gridDim.y;
  const u32 bid = blockIdx.y * gridDim.x + blockIdx.x;  // m-fastest linearization
  const u32 sid = (bid & 7u) * (nwg >> 3) + (bid >> 3);
  const int m0 = (int)(sid % gridDim.x) * 64;
  const int n0 = (int)(sid / gridDim.x) * 128;

  const int wm = (w >> 1) * 32, wn = (w & 1) * 64;

  const u16* gp[6];
  u32 lo[6];
#pragma unroll
  for (int j = 0; j < 6; ++j) {
    u32 u = (u32)t * 16u + (u32)j * 4096u;
    u32 row = u >> 7;
    u32 slot = ((u >> 4) & 7u) ^ (row & 7u);
    lo[j] = u;
    gp[j] = (row < 64 ? A + (size_t)(m0 + (int)row) * K
                      : BT + (size_t)(n0 + (int)(row - 64)) * K) + slot * 8;
  }
  auto stage = [&](int b, int k0) {
#pragma unroll
    for (int j = 0; j < 6; ++j) async16(gp[j] + k0, (char*)S[b] + lo[j]);
  };

  f32x4 acc[2][4];
#pragma unroll
  for (int i = 0; i < 2; ++i)
#pragma unroll
    for (int j = 0; j < 4; ++j) acc[i][j] = (f32x4){0.f, 0.f, 0.f, 0.f};

  stage(0, 0);
  __syncthreads();

  const int nit = K / 64;
#pragma unroll 2
  for (int it = 0; it < nit; ++it) {
    const int cur = it & 1;
    if (it + 1 < nit) stage(cur ^ 1, (it + 1) * 64);  // loads fly under compute

    s16x8 af[2][2], bq[4][2];
#pragma unroll
    for (int mt = 0; mt < 2; ++mt) {
      u32 r = (u32)(wm + mt * 16 + ll);
#pragma unroll
      for (int ks = 0; ks < 2; ++ks)
        af[mt][ks] = *(const s16x8*)((const char*)S[cur] + r * 128u +
                                     ((((u32)(ks * 4 + lg)) ^ (r & 7u)) * 16u));
    }
#pragma unroll
    for (int nt = 0; nt < 4; ++nt) {
      u32 r = (u32)(64 + wn + nt * 16 + ll);
#pragma unroll
      for (int ks = 0; ks < 2; ++ks)
        bq[nt][ks] = *(const s16x8*)((const char*)S[cur] + r * 128u +
                                     ((((u32)(ks * 4 + lg)) ^ (r & 7u)) * 16u));
    }
#pragma unroll
    for (int ks = 0; ks < 2; ++ks)
#pragma unroll
      for (int mt = 0; mt < 2; ++mt)
#pragma unroll
        for (int nt = 0; nt < 4; ++nt)
          acc[mt][nt] = __builtin_amdgcn_mfma_f32_16x16x32_bf16(af[mt][ks], bq[nt][ks],
                                                                acc[mt][nt], 0, 0, 0);
    __syncthreads();
  }

  if (MODE == 1) {
#pragma unroll
    for (int mt = 0; mt < 2; ++mt) {
      int srow = m0 + wm + mt * 16 + lg * 4;
#pragma unroll
      for (int nt = 0; nt < 4; ++nt) {
        int col = n0 + wn + nt * 16 + ll;
        f32x4 a = acc[mt][nt];
#pragma unroll
        for (int j = 0; j < 4; ++j) Cf[(size_t)(srow + j) * N + col] = a[j];
      }
    }
  } else {
#pragma unroll
    for (int nt = 0; nt < 4; ++nt) {
      int cb = n0 + wn + nt * 16;  // wave-uniform
#pragma unroll
      for (int mt = 0; mt < 2; ++mt) {
        int srow = m0 + wm + mt * 16 + lg * 4;
        f32x4 a = acc[mt][nt];
        if (cb < 2048) {
          int hh = cb >> 7, d = (cb & 127) + ll;
          u16* p = qr + ((size_t)hh * S_LEN) * HD + d;
#pragma unroll
          for (int j = 0; j < 4; ++j) p[(size_t)(srow + j) * HD] = f2bf(a[j]);
        } else if (cb < 2560) {
          int hh = (cb - 2048) >> 7, d = ((cb - 2048) & 127) + ll;
          u16* p = kr + ((size_t)hh * S_LEN) * HD + d;
#pragma unroll
          for (int j = 0; j < 4; ++j) p[(size_t)(srow + j) * HD] = f2bf(a[j]);
        } else {
          int hh = (cb - 2560) >> 7, d = ((cb - 2560) & 127) + ll;
          ushort4 pk;
          pk.x = f2bf(a[0]); pk.y = f2bf(a[1]); pk.z = f2bf(a[2]); pk.w = f2bf(a[3]);
          *(ushort4*)(vt + ((size_t)hh * HD + d) * S_LEN + srow) = pk;
        }
      }
    }
  }
}

// ---------------- attention ----------------
// Head-sharing grid: block = 16 q rows x ALL 4 heads of one KV group
// (grid (S/16, NKV), wave w = head hkv*4+w). All waves share one key window
// [kbeg, qs+15] -> zero wave-idle chunks, uniform masks, K/V staged once for
// 4 heads. 3-buffer counted-vmcnt pipeline in both passes (2-ahead, stage
// issued AFTER barrier; buffer distance 2 is race-free: readers of buf
// (tc+2)%3 finished at barrier(tc)).
// Pass 1: K-only 64-key tiles. Pass 2: 32-key tiles, buf = K(8KB)+V(8KB).
// Q-RoPE (+QSCALE exp2-domain fold) in-register. No-max exp2 softmax.
__global__ __launch_bounds__(256, 3) void k_attn(const u16* __restrict__ qr,
                                                 const u16* __restrict__ kr,
                                                 const u16* __restrict__ vt,
                                                 const float* __restrict__ lam,
                                                 const float2* __restrict__ cs,
                                                 u16* __restrict__ ao) {
  __shared__ u16 KV[3][8192];   // 3 x 16KB
  __shared__ u16 P[4][16 * 40]; // per-wave P^T tile, row stride 40 u16 (80B)
  const int t = threadIdx.x;
  const int l = t & 63, w = t >> 6;
  const int lg = l >> 4, ll = l & 15;
  const int hkv = blockIdx.y;
  const int h = hkv * 4 + w;        // this wave's head
  const int qs = blockIdx.x * 16;   // block-shared q range [qs, qs+16)
  const int row = qs + ll;          // this lane's q row (same for all waves)

  const u16* Qp = qr + ((size_t)h * S_LEN + qs) * HD;
  const u16* Kp = kr + (size_t)hkv * S_LEN * HD;
  const u16* Vp = vt + (size_t)hkv * HD * S_LEN;

  const int kbeg = (qs >= 512) ? ((qs - 511) & ~63) : 0;
  const int nch1 = (qs + 15 - kbeg) / 64 + 1;  // 64-key chunks (pass 1)
  const int nch2 = (qs + 15 - kbeg) / 32 + 1;  // 32-key chunks (pass 2)

  // pass-1 staging coords (16KB tile: 64 rows x 256B, 16 slots, slot ^= row&7)
  u32 ku1[4], kr1[4], ks1[4];
#pragma unroll
  for (int j = 0; j < 4; ++j) {
    u32 u = (u32)t * 16u + (u32)j * 4096u;
    ku1[j] = u;
    kr1[j] = u >> 8;
    ks1[j] = ((u >> 4) & 15u) ^ (kr1[j] & 7u);
  }
  // pass-2 K coords (8KB: 32 rows x 256B) and V coords (8KB: 64 LDS rows x
  // 128B; LDS row r = d rows 2r,2r+1; logical slot = phys ^ (r&7))
  u32 ku2[2], kr2[2], ks2[2], vu2[2], vd2[2], vk2[2];
#pragma unroll
  for (int j = 0; j < 2; ++j) {
    u32 u = (u32)t * 16u + (u32)j * 4096u;
    ku2[j] = u;
    kr2[j] = u >> 8;
    ks2[j] = ((u >> 4) & 15u) ^ (kr2[j] & 7u);
    u32 r = u >> 7;
    u32 lgc = ((u >> 4) & 7u) ^ (r & 7u);
    vu2[j] = u;
    vd2[j] = 2u * r + (lgc >> 2);
    vk2[j] = (lgc & 3u) * 8u;
  }

  auto stage1 = [&](int buf, int tcc) {
    const int c = kbeg + tcc * 64;
    char* dst = (char*)KV + (size_t)buf * 16384;
#pragma unroll
    for (int j = 0; j < 4; ++j)
      async16(Kp + (size_t)(c + kr1[j]) * HD + ks1[j] * 8, dst + ku1[j]);
  };
  auto stage2 = [&](int buf, int tcc) {
    const int c = kbeg + tcc * 32;
    char* dst = (char*)KV + (size_t)buf * 16384;
#pragma unroll
    for (int j = 0; j < 2; ++j) {
      async16(Kp + (size_t)(c + kr2[j]) * HD + ks2[j] * 8, dst + ku2[j]);
      async16(Vp + (size_t)vd2[j] * S_LEN + c + vk2[j], dst + 8192 + vu2[j]);
    }
  };

  // ---- Q fragments + in-register RoPE (+QSCALE) ----
  s16x8 qa[4];
#pragma unroll
  for (int i = 0; i < 4; ++i)
    qa[i] = *(const s16x8*)(Qp + (size_t)ll * HD + i * 32 + lg * 8);
  {
    const float4* cp4 = (const float4*)(cs + (size_t)row * 64);  // 32 float4/row
#pragma unroll
    for (int i = 0; i < 2; ++i) {
      float4 cv[4];
#pragma unroll
      for (int jj = 0; jj < 4; ++jj) cv[jj] = cp4[i * 16 + lg * 4 + jj];
      s16x8 lo = qa[i], hi = qa[i + 2];
#pragma unroll
      for (int j = 0; j < 8; ++j) {
        float cc = (j & 1) ? cv[j >> 1].z : cv[j >> 1].x;
        float ss = (j & 1) ? cv[j >> 1].w : cv[j >> 1].y;
        float a = bf2f((u16)lo[j]), b = bf2f((u16)hi[j]);
        lo[j] = (short)f2bf((a * cc - b * ss) * QSCALE);
        hi[j] = (short)f2bf((b * cc + a * ss) * QSCALE);
      }
      qa[i] = lo; qa[i + 2] = hi;
    }
  }

  const f32x4 zero = {0.f, 0.f, 0.f, 0.f};
  float z1 = 0.f, z2 = 0.f;

  // ---- pass 1: Z sums (3-buf K, counted vmcnt, 2-ahead) ----
  stage1(0, 0);
  stage1(1, (nch1 > 1) ? 1 : 0);

  for (int tc = 0; tc < nch1; ++tc) {
    WAIT_VMCNT4;                    // own stage tc landed (in-order vmem)
    __builtin_amdgcn_s_barrier();   // all waves' stage tc landed
    {
      int ci = tc + 2; if (ci > nch1 - 1) ci = nch1 - 1;  // clamped, uniform
      stage1((tc + 2) % 3, ci);
    }
    const int c = kbeg + tc * 64;
    const u16* Kb = (const u16*)((const char*)KV + (size_t)(tc % 3) * 16384);
    float acc1 = 0.f, acc2 = 0.f;
#pragma unroll
    for (int kt = 0; kt < 4; ++kt) {
      const int kbase = c + kt * 16;
      if (kbase > qs + 15 || kbase + 15 < qs - (WIN - 1)) continue;  // uniform
      const int kr_ = kt * 16 + ll;
      const u16* kp = Kb + kr_ * 128;
      const u32 sw = (u32)(kr_ & 7);
      s16x8 b0 = *(const s16x8*)(kp + ((lg ^ sw) * 8));
      s16x8 b1 = *(const s16x8*)(kp + (((4 + lg) ^ sw) * 8));
      s16x8 b2 = *(const s16x8*)(kp + (((8 + lg) ^ sw) * 8));
      s16x8 b3 = *(const s16x8*)(kp + (((12 + lg) ^ sw) * 8));
      f32x4 a = __builtin_amdgcn_mfma_f32_16x16x32_bf16(b0, qa[0], zero, 0, 0, 0);
      a = __builtin_amdgcn_mfma_f32_16x16x32_bf16(b1, qa[1], a, 0, 0, 0);
      f32x4 b = __builtin_amdgcn_mfma_f32_16x16x32_bf16(b2, qa[2], zero, 0, 0, 0);
      b = __builtin_amdgcn_mfma_f32_16x16x32_bf16(b3, qa[3], b, 0, 0, 0);
      const bool fullk = (kbase + 15 <= qs) && (kbase >= qs - 496);
      if (!fullk) {
#pragma unroll
        for (int j = 0; j < 4; ++j) {
          int key = kbase + lg * 4 + j;
          bool ok = (key <= row) && (key > row - WIN);
          a[j] = ok ? a[j] : -1e30f;
          b[j] = ok ? b[j] : -1e30f;
        }
      }
#pragma unroll
      for (int j = 0; j < 4; ++j) {
        acc1 += __builtin_amdgcn_exp2f(a[j]);  // exp2(-1e30) flushes to 0
        acc2 += __builtin_amdgcn_exp2f(b[j]);
      }
    }
    z1 += acc1; z2 += acc2;
  }

  // merge the 4 lg-group partials (lanes ll, ll+16, ll+32, ll+48 share q=ll)
  z1 += __shfl_xor(z1, 16, 64); z1 += __shfl_xor(z1, 32, 64);
  z2 += __shfl_xor(z2, 16, 64); z2 += __shfl_xor(z2, 32, 64);
  const float l2z1 = __builtin_amdgcn_logf(z1);  // v_log_f32 = log2
  const float l2z2 = __builtin_amdgcn_logf(z2);
  const float lm = lam[h];

  // ---- pass 2: diff-combine + PV (3-buf K8+V8, counted vmcnt, 2-ahead) ----
  f32x4 o[8];
#pragma unroll
  for (int dt = 0; dt < 8; ++dt) o[dt] = zero;
  float dsum = 0.f;
  u16* Pw = &P[w][0];

  WAIT_VMCNT0;      // pass-1 trailing stages landed
  __syncthreads();  // all waves done with pass-1 buffers

  stage2(0, 0);
  stage2(1, (nch2 > 1) ? 1 : 0);

  for (int tc = 0; tc < nch2; ++tc) {
    WAIT_VMCNT4;                    // own stage tc landed
    __builtin_amdgcn_s_barrier();   // all waves' stage tc landed
    {
      int ci = tc + 2; if (ci > nch2 - 1) ci = nch2 - 1;  // clamped, uniform
      stage2((tc + 2) % 3, ci);
    }
    const int c = kbeg + tc * 32;
    const u16* Kb = (const u16*)((const char*)KV + (size_t)(tc % 3) * 16384);
    const u16* Vb = Kb + 4096;  // +8KB
    const bool full = (c + 31 <= qs) && (c >= qs - 496);
    __builtin_amdgcn_s_setprio(1);
#pragma unroll
    for (int kt = 0; kt < 2; ++kt) {
      const int kr_ = kt * 16 + ll;
      const u16* kp = Kb + kr_ * 128;
      const u32 sw = (u32)(kr_ & 7);
      s16x8 b0 = *(const s16x8*)(kp + ((lg ^ sw) * 8));
      s16x8 b1 = *(const s16x8*)(kp + (((4 + lg) ^ sw) * 8));
      s16x8 b2 = *(const s16x8*)(kp + (((8 + lg) ^ sw) * 8));
      s16x8 b3 = *(const s16x8*)(kp + (((12 + lg) ^ sw) * 8));
      f32x4 a = __builtin_amdgcn_mfma_f32_16x16x32_bf16(b0, qa[0], zero, 0, 0, 0);
      a = __builtin_amdgcn_mfma_f32_16x16x32_bf16(b1, qa[1], a, 0, 0, 0);
      f32x4 b = __builtin_amdgcn_mfma_f32_16x16x32_bf16(b2, qa[2], zero, 0, 0, 0);
      b = __builtin_amdgcn_mfma_f32_16x16x32_bf16(b3, qa[3], b, 0, 0, 0);
      if (!full) {
#pragma unroll
        for (int j = 0; j < 4; ++j) {
          int key = c + kt * 16 + lg * 4 + j;
          bool ok = (key <= row) && (key > row - WIN);
          a[j] = ok ? a[j] : -1e30f;
          b[j] = ok ? b[j] : -1e30f;
        }
      }
      float d4[4];
#pragma unroll
      for (int j = 0; j < 4; ++j) {
        float a1 = __builtin_amdgcn_exp2f(a[j] - l2z1);
        float a2 = __builtin_amdgcn_exp2f(b[j] - l2z2);
        float d = fmaxf(fmaf(-lm, a2, a1), 0.f);
        d4[j] = d;
        dsum += d;
      }
      u32 p01, p23;
      asm("v_cvt_pk_bf16_f32 %0, %1, %2" : "=v"(p01) : "v"(d4[0]), "v"(d4[1]));
      asm("v_cvt_pk_bf16_f32 %0, %1, %2" : "=v"(p23) : "v"(d4[2]), "v"(d4[3]));
      uint2 pk; pk.x = p01; pk.y = p23;
      *(uint2*)(&Pw[ll * 40 + kt * 16 + lg * 4]) = pk;
    }
    // per-wave LDS transpose round-trip (wave-synchronous; compiler waits lgkm)
    s16x8 pf = *(const s16x8*)(&Pw[ll * 40 + lg * 8]);
#pragma unroll
    for (int dt = 0; dt < 8; ++dt) {
      const int d = dt * 16 + ll;
      const u32 r = (u32)(d >> 1);
      const u32 phys = ((u32)((d & 1) * 4 + lg)) ^ (r & 7u);
      s16x8 vf = *(const s16x8*)(Vb + r * 64 + phys * 8);
      o[dt] = __builtin_amdgcn_mfma_f32_16x16x32_bf16(pf, vf, o[dt], 0, 0, 0);
    }
    __builtin_amdgcn_s_setprio(0);
  }
  WAIT_VMCNT0;  // drain trailing stages before kernel end

  // dsum: merge lg partials, then fetch 1/(sum+eps) for output rows lg*4+j
  dsum += __shfl_xor(dsum, 16, 64);
  dsum += __shfl_xor(dsum, 32, 64);
  const float rds = __builtin_amdgcn_rcpf(dsum + 1e-6f);
  float rdsj[4];
#pragma unroll
  for (int j = 0; j < 4; ++j) rdsj[j] = __shfl(rds, lg * 4 + j, 64);

#pragma unroll
  for (int dt = 0; dt < 8; ++dt) {
#pragma unroll
    for (int j = 0; j < 4; ++j) {
      int srow = qs + lg * 4 + j;
      ao[(size_t)srow * DMODEL + h * HD + dt * 16 + ll] = f2bf(o[dt][j] * rdsj[j]);
    }
  }
}

// ---------------- launch ----------------

extern "C" void kernel_launch(void* const* d_in, const int* in_sizes, int n_in,
                              void* d_out, int out_size, void* d_ws, size_t ws_size,
                              hipStream_t stream) {
  const float* x = (const float*)d_in[0];
  const float* Wq = (const float*)d_in[1];
  const float* Wk = (const float*)d_in[2];
  const float* Wv = (const float*)d_in[3];
  const float* Wo = (const float*)d_in[4];
  const float* lam = (const float*)d_in[5];
  float* out = (float*)d_out;

  char* ws = (char*)d_ws;
  u16* xb = (u16*)(ws);                               // 8 MB  [2048][2048]
  u16* WT = (u16*)(ws + (8u << 20));                  // 12 MB [3072][2048] (Wq^T|Wk^T|Wv^T)
  u16* WoT = (u16*)(ws + (20u << 20));                // 8 MB  [2048][2048]
  u16* qr = (u16*)(ws + (28u << 20));                 // 8 MB  [16][2048][128]
  u16* kr = (u16*)(ws + (36u << 20));                 // 2 MB  [4][2048][128]
  u16* vt = (u16*)(ws + (38u << 20));                 // 2 MB  [4][128][2048]
  u16* ao = (u16*)(ws + (40u << 20));                 // 8 MB  [2048][2048]
  float2* cs = (float2*)(ws + (48u << 20));           // 1 MB  [2048][64]

  k_prep<<<14848, 256, 0, stream>>>(x, xb, Wq, Wk, Wv, Wo, WT, WoT, cs);

  k_gemm<0><<<dim3(32, 24), 256, 0, stream>>>(xb, WT, nullptr, 2048, 3072, qr, kr, vt);

  // K roped in-place; Q-rope (+QSCALE, exp2-domain fold) fused into k_attn
  k_rope_k<<<(NKV * S_LEN * 64) / 256, 256, 0, stream>>>(kr, cs);

  k_attn<<<dim3(S_LEN / 16, NKV), 256, 0, stream>>>(qr, kr, vt, lam, cs, ao);

  k_gemm<1><<<dim3(32, 16), 256, 0, stream>>>(ao, WoT, out, 2048, 2048, nullptr, nullptr, nullptr);
}

// Round 14
// 104.726 us; speedup vs baseline: 1.2672x; 1.1009x over previous
//
#include <hip/hip_runtime.h>

typedef unsigned int u32;
typedef unsigned short u16;
typedef __attribute__((ext_vector_type(4))) float f32x4;
typedef __attribute__((ext_vector_type(8))) short s16x8;

#define S_LEN 2048
#define DMODEL 2048
#define NH 16
#define NKV 4
#define HD 128
#define WIN 512
// 0.125 (1/sqrt(64)) * log2(e): folds score scale + exp2-domain conversion into Q
#define QSCALE 0.18033688011112042f

#define WAIT_VMCNT4 asm volatile("s_waitcnt vmcnt(4)" ::: "memory")
#define WAIT_VMCNT0 asm volatile("s_waitcnt vmcnt(0)" ::: "memory")

__device__ __forceinline__ u16 f2bf(float f) {
  union { float f; u32 u; } v; v.f = f;
  u32 r = v.u + 0x7FFFu + ((v.u >> 16) & 1u);
  return (u16)(r >> 16);
}
__device__ __forceinline__ float bf2f(u16 h) {
  union { u32 u; float f; } v; v.u = ((u32)h) << 16;
  return v.f;
}
__device__ __forceinline__ float bflo(u32 p) {  // low bf16 of packed pair
  union { u32 u; float f; } v; v.u = p << 16;
  return v.f;
}
__device__ __forceinline__ float bfhi(u32 p) {  // high bf16 of packed pair
  union { u32 u; float f; } v; v.u = p & 0xFFFF0000u;
  return v.f;
}

__device__ __forceinline__ void async16(const void* g, void* l) {
  __builtin_amdgcn_global_load_lds((const __attribute__((address_space(1))) void*)g,
                                   (__attribute__((address_space(3))) void*)l, 16, 0, 0);
}

// ---------------- prep kernel ----------------
// bid < 4096: x f32->bf16 convert. 4096..14336: weight transposes
// (Wq 4096 | Wk 1024 | Wv 1024 | Wo 4096). >=14336: rope cos/sin table.
__global__ __launch_bounds__(256) void k_prep(const float* __restrict__ x, u16* __restrict__ xb,
                                              const float* __restrict__ Wq,
                                              const float* __restrict__ Wk,
                                              const float* __restrict__ Wv,
                                              const float* __restrict__ Wo,
                                              u16* __restrict__ WT, u16* __restrict__ WoT,
                                              float2* __restrict__ cs) {
  __shared__ float tile[32][33];
  const int bid = blockIdx.x;
  if (bid >= 14336) {  // rope table: 512 blocks x 4 s-rows x 64 d
    int s = (bid - 14336) * 4 + (threadIdx.x >> 6);
    int d = threadIdx.x & 63;
    float invf = expf(-((float)(2 * d) / (float)HD) * logf(10000.0f));
    float fr = (float)s * invf;
    float sv, cv;
    sincosf(fr, &sv, &cv);
    cs[s * 64 + d] = make_float2(cv, sv);
    return;
  }
  if (bid < 4096) {
    int i = bid * 256 + threadIdx.x;
    float4 v = ((const float4*)x)[i];
    ushort4 o;
    o.x = f2bf(v.x); o.y = f2bf(v.y); o.z = f2bf(v.z); o.w = f2bf(v.w);
    ((ushort4*)xb)[i] = o;
    return;
  }
  const int b = bid - 4096;
  const float* src;
  u16* dst;
  int N, nt, kt;
  if (b < 4096) {
    src = Wq; dst = WT; N = 2048; nt = b & 63; kt = b >> 6;
  } else if (b < 5120) {
    int i = b - 4096;
    src = Wk; dst = WT + (size_t)2048 * 2048; N = 512; nt = i & 15; kt = i >> 4;
  } else if (b < 6144) {
    int i = b - 5120;
    src = Wv; dst = WT + (size_t)2560 * 2048; N = 512; nt = i & 15; kt = i >> 4;
  } else {
    int i = b - 6144;
    src = Wo; dst = WoT; N = 2048; nt = i & 63; kt = i >> 6;
  }
  const int tx = threadIdx.x & 31, ty = threadIdx.x >> 5;
  const int n0 = nt * 32, k0 = kt * 32;
#pragma unroll
  for (int i = 0; i < 4; ++i)
    tile[ty + 8 * i][tx] = src[(size_t)(k0 + ty + 8 * i) * N + n0 + tx];
  __syncthreads();
#pragma unroll
  for (int i = 0; i < 4; ++i)
    dst[(size_t)(n0 + ty + 8 * i) * 2048 + k0 + tx] = f2bf(tile[tx][ty + 8 * i]);
}

// rope in-place on kr only (Q-rope fused into k_attn). grid exact: 2048 blocks.
__global__ void k_rope_k(u16* __restrict__ kr, const float2* __restrict__ cs) {
  int i = blockIdx.x * blockDim.x + threadIdx.x;
  int rowg = i >> 6, d = i & 63;
  int s = rowg & (S_LEN - 1);
  float2 c = cs[s * 64 + d];
  u16* p = kr + (size_t)rowg * HD;
  float a = bf2f(p[d]), b = bf2f(p[d + 64]);
  p[d]      = f2bf(a * c.x - b * c.y);
  p[d + 64] = f2bf(b * c.x + a * c.y);
}

// ---------------- GEMM (BK=64, 2-buf T3-min, 3 blocks/CU) ----------------
// A [M][K] bf16 row-major, BT [N][K] bf16. 64x128 tile, BK=64, 4 waves (2x2 of
// 32x64), double-buffered LDS (T3-min), chunked XCD swizzle.
// MODE 0: scatter epilogue -> qr[h][s][d], kr[h][s][d], vt[h][d][s]
// MODE 1: plain fp32 C[M][N]

template <int MODE>
__global__ __launch_bounds__(256) void k_gemm(const u16* __restrict__ A, const u16* __restrict__ BT,
                                              float* __restrict__ Cf, int K, int N,
                                              u16* __restrict__ qr, u16* __restrict__ kr,
                                              u16* __restrict__ vt) {
  // A rows 0..63, B rows 64..191; each row 64 u16 = 128B; 24KB per buffer
  __shared__ u16 S[2][192 * 64];
  const int t = threadIdx.x;
  const int l = t & 63, w = t >> 6;
  const int lg = l >> 4, ll = l & 15;

  // chunked XCD swizzle (bijective: nwg % 8 == 0 for both call sites)
  const u32 nwg = gridDim.x * gridDim.y;
  const u32 bid = blockIdx.y * gridDim.x + blockIdx.x;  // m-fastest linearization
  const u32 sid = (bid & 7u) * (nwg >> 3) + (bid >> 3);
  const int m0 = (int)(sid % gridDim.x) * 64;
  const int n0 = (int)(sid / gridDim.x) * 128;

  const int wm = (w >> 1) * 32, wn = (w & 1) * 64;

  const u16* gp[6];
  u32 lo[6];
#pragma unroll
  for (int j = 0; j < 6; ++j) {
    u32 u = (u32)t * 16u + (u32)j * 4096u;
    u32 row = u >> 7;
    u32 slot = ((u >> 4) & 7u) ^ (row & 7u);
    lo[j] = u;
    gp[j] = (row < 64 ? A + (size_t)(m0 + (int)row) * K
                      : BT + (size_t)(n0 + (int)(row - 64)) * K) + slot * 8;
  }
  auto stage = [&](int b, int k0) {
#pragma unroll
    for (int j = 0; j < 6; ++j) async16(gp[j] + k0, (char*)S[b] + lo[j]);
  };

  f32x4 acc[2][4];
#pragma unroll
  for (int i = 0; i < 2; ++i)
#pragma unroll
    for (int j = 0; j < 4; ++j) acc[i][j] = (f32x4){0.f, 0.f, 0.f, 0.f};

  stage(0, 0);
  __syncthreads();

  const int nit = K / 64;
#pragma unroll 2
  for (int it = 0; it < nit; ++it) {
    const int cur = it & 1;
    if (it + 1 < nit) stage(cur ^ 1, (it + 1) * 64);  // loads fly under compute

    s16x8 af[2][2], bq[4][2];
#pragma unroll
    for (int mt = 0; mt < 2; ++mt) {
      u32 r = (u32)(wm + mt * 16 + ll);
#pragma unroll
      for (int ks = 0; ks < 2; ++ks)
        af[mt][ks] = *(const s16x8*)((const char*)S[cur] + r * 128u +
                                     ((((u32)(ks * 4 + lg)) ^ (r & 7u)) * 16u));
    }
#pragma unroll
    for (int nt = 0; nt < 4; ++nt) {
      u32 r = (u32)(64 + wn + nt * 16 + ll);
#pragma unroll
      for (int ks = 0; ks < 2; ++ks)
        bq[nt][ks] = *(const s16x8*)((const char*)S[cur] + r * 128u +
                                     ((((u32)(ks * 4 + lg)) ^ (r & 7u)) * 16u));
    }
#pragma unroll
    for (int ks = 0; ks < 2; ++ks)
#pragma unroll
      for (int mt = 0; mt < 2; ++mt)
#pragma unroll
        for (int nt = 0; nt < 4; ++nt)
          acc[mt][nt] = __builtin_amdgcn_mfma_f32_16x16x32_bf16(af[mt][ks], bq[nt][ks],
                                                                acc[mt][nt], 0, 0, 0);
    __syncthreads();
  }

  if (MODE == 1) {
#pragma unroll
    for (int mt = 0; mt < 2; ++mt) {
      int srow = m0 + wm + mt * 16 + lg * 4;
#pragma unroll
      for (int nt = 0; nt < 4; ++nt) {
        int col = n0 + wn + nt * 16 + ll;
        f32x4 a = acc[mt][nt];
#pragma unroll
        for (int j = 0; j < 4; ++j) Cf[(size_t)(srow + j) * N + col] = a[j];
      }
    }
  } else {
#pragma unroll
    for (int nt = 0; nt < 4; ++nt) {
      int cb = n0 + wn + nt * 16;  // wave-uniform
#pragma unroll
      for (int mt = 0; mt < 2; ++mt) {
        int srow = m0 + wm + mt * 16 + lg * 4;
        f32x4 a = acc[mt][nt];
        if (cb < 2048) {
          int hh = cb >> 7, d = (cb & 127) + ll;
          u16* p = qr + ((size_t)hh * S_LEN) * HD + d;
#pragma unroll
          for (int j = 0; j < 4; ++j) p[(size_t)(srow + j) * HD] = f2bf(a[j]);
        } else if (cb < 2560) {
          int hh = (cb - 2048) >> 7, d = ((cb - 2048) & 127) + ll;
          u16* p = kr + ((size_t)hh * S_LEN) * HD + d;
#pragma unroll
          for (int j = 0; j < 4; ++j) p[(size_t)(srow + j) * HD] = f2bf(a[j]);
        } else {
          int hh = (cb - 2560) >> 7, d = ((cb - 2560) & 127) + ll;
          ushort4 pk;
          pk.x = f2bf(a[0]); pk.y = f2bf(a[1]); pk.z = f2bf(a[2]); pk.w = f2bf(a[3]);
          *(ushort4*)(vt + ((size_t)hh * HD + d) * S_LEN + srow) = pk;
        }
      }
    }
  }
}

// ---------------- attention ----------------
// Single-QK^T formulation: d = relu(a1 - lm*a2) = relu(e1 - c*e2)/z1 with
// c = lm*z1/z2 and e = exp2(score) UNNORMALIZED, so pass 2 needs no K, no
// QK^T MFMA, and no exp -- phase A caches packed-bf16 e1,e2 in REGISTERS
// (p[9][16] = 144 VGPRs; free because the grid caps occupancy at 2 waves/SIMD
// anyway). Output: out = sum(u*v) / (sum(u) + z1*1e-6), u = relu(e1 - c*e2).
// Head-sharing grid (S/16, NKV), wave w = head hkv*4+w. Both phases: fixed 9
// unrolled 64-key chunks (static p indexing), uniform guards, 3-buffer
// counted-vmcnt pipeline (2-ahead, clamped tail stages).
// Phase A: K tiles (64 rows x 256B, XOR-swz). Phase B: V tiles ([d=128][k=64]
// 128B rows, XOR-swz) reusing the same buffers. Q-RoPE in-register.
__global__ __launch_bounds__(256, 2) void k_attn(const u16* __restrict__ qr,
                                                 const u16* __restrict__ kr,
                                                 const u16* __restrict__ vt,
                                                 const float* __restrict__ lam,
                                                 const float2* __restrict__ cs,
                                                 u16* __restrict__ ao) {
  __shared__ u16 KV[3][8192];   // 3 x 16KB: phase A = K bufs, phase B = V bufs
  __shared__ u16 P[4][16 * 72]; // per-wave u^T transpose tile (16 q x 64 keys)
  const int t = threadIdx.x;
  const int l = t & 63, w = t >> 6;
  const int lg = l >> 4, ll = l & 15;
  const int hkv = blockIdx.y;
  const int h = hkv * 4 + w;        // this wave's head
  const int qs = blockIdx.x * 16;   // block-shared q range [qs, qs+16)
  const int row = qs + ll;          // this lane's q row

  const u16* Qp = qr + ((size_t)h * S_LEN + qs) * HD;
  const u16* Kp = kr + (size_t)hkv * S_LEN * HD;
  const u16* Vp = vt + (size_t)hkv * HD * S_LEN;

  const int kbeg = (qs >= 512) ? ((qs - 511) & ~63) : 0;
  const int nch = (qs + 15 - kbeg) / 64 + 1;  // 1..9 64-key chunks

  // K staging coords (16KB tile: 64 rows x 256B, 16 slots, slot ^= row&7)
  u32 ku1[4], kr1[4], ks1[4];
#pragma unroll
  for (int j = 0; j < 4; ++j) {
    u32 u = (u32)t * 16u + (u32)j * 4096u;
    ku1[j] = u;
    kr1[j] = u >> 8;
    ks1[j] = ((u >> 4) & 15u) ^ (kr1[j] & 7u);
  }
  // V staging coords (16KB tile: 128 d-rows x 128B, 8 slots, slot ^= d&7)
  u32 vu[4], vdr[4], vsl[4];
#pragma unroll
  for (int j = 0; j < 4; ++j) {
    u32 u = (u32)t * 16u + (u32)j * 4096u;
    vu[j] = u;
    vdr[j] = u >> 7;
    vsl[j] = ((u >> 4) & 7u) ^ (vdr[j] & 7u);
  }

  auto stageK = [&](int buf, int tcc) {
    const int c = kbeg + tcc * 64;
    char* dst = (char*)KV + (size_t)buf * 16384;
#pragma unroll
    for (int j = 0; j < 4; ++j)
      async16(Kp + (size_t)(c + kr1[j]) * HD + ks1[j] * 8, dst + ku1[j]);
  };
  auto stageV = [&](int buf, int tcc) {
    const int c = kbeg + tcc * 64;
    char* dst = (char*)KV + (size_t)buf * 16384;
#pragma unroll
    for (int j = 0; j < 4; ++j)
      async16(Vp + (size_t)vdr[j] * S_LEN + c + vsl[j] * 8, dst + vu[j]);
  };

  // ---- Q fragments + in-register RoPE (+QSCALE) ----
  s16x8 qa[4];
#pragma unroll
  for (int i = 0; i < 4; ++i)
    qa[i] = *(const s16x8*)(Qp + (size_t)ll * HD + i * 32 + lg * 8);
  {
    const float4* cp4 = (const float4*)(cs + (size_t)row * 64);  // 32 float4/row
#pragma unroll
    for (int i = 0; i < 2; ++i) {
      float4 cv[4];
#pragma unroll
      for (int jj = 0; jj < 4; ++jj) cv[jj] = cp4[i * 16 + lg * 4 + jj];
      s16x8 lo = qa[i], hi = qa[i + 2];
#pragma unroll
      for (int j = 0; j < 8; ++j) {
        float cc = (j & 1) ? cv[j >> 1].z : cv[j >> 1].x;
        float ss = (j & 1) ? cv[j >> 1].w : cv[j >> 1].y;
        float a = bf2f((u16)lo[j]), b = bf2f((u16)hi[j]);
        lo[j] = (short)f2bf((a * cc - b * ss) * QSCALE);
        hi[j] = (short)f2bf((b * cc + a * ss) * QSCALE);
      }
      qa[i] = lo; qa[i + 2] = hi;
    }
  }

  const f32x4 zero = {0.f, 0.f, 0.f, 0.f};
  float z1 = 0.f, z2 = 0.f;
  u32 p[9][16];  // packed bf16: [tc][0..7]=e1 pairs, [tc][8..15]=e2 pairs

  // ---- phase A: QK^T + exp2, cache e's in regs, accumulate z ----
  stageK(0, 0);
  stageK(1, (nch > 1) ? 1 : 0);

#pragma unroll
  for (int tc = 0; tc < 9; ++tc) {
    WAIT_VMCNT4;                    // own stage tc landed (in-order vmem)
    __builtin_amdgcn_s_barrier();   // all waves' stage tc landed
    {
      int ci = tc + 2; if (ci > nch - 1) ci = nch - 1;  // clamped, uniform
      stageK((tc + 2) % 3, ci);
    }
    if (tc < nch) {  // uniform within block
      const int c = kbeg + tc * 64;
      const u16* Kb = (const u16*)((const char*)KV + (size_t)(tc % 3) * 16384);
      float acc1 = 0.f, acc2 = 0.f;
#pragma unroll
      for (int kt = 0; kt < 4; ++kt) {
        const int kbase = c + kt * 16;
        if (kbase > qs + 15 || kbase + 15 < qs - (WIN - 1)) continue;  // uniform; phase B skips same
        const int kr_ = kt * 16 + ll;
        const u16* kp = Kb + kr_ * 128;
        const u32 sw = (u32)(kr_ & 7);
        s16x8 b0 = *(const s16x8*)(kp + ((lg ^ sw) * 8));
        s16x8 b1 = *(const s16x8*)(kp + (((4 + lg) ^ sw) * 8));
        s16x8 b2 = *(const s16x8*)(kp + (((8 + lg) ^ sw) * 8));
        s16x8 b3 = *(const s16x8*)(kp + (((12 + lg) ^ sw) * 8));
        f32x4 a = __builtin_amdgcn_mfma_f32_16x16x32_bf16(b0, qa[0], zero, 0, 0, 0);
        a = __builtin_amdgcn_mfma_f32_16x16x32_bf16(b1, qa[1], a, 0, 0, 0);
        f32x4 b = __builtin_amdgcn_mfma_f32_16x16x32_bf16(b2, qa[2], zero, 0, 0, 0);
        b = __builtin_amdgcn_mfma_f32_16x16x32_bf16(b3, qa[3], b, 0, 0, 0);
        const bool fullk = (kbase + 15 <= qs) && (kbase >= qs - 496);
        if (!fullk) {
#pragma unroll
          for (int j = 0; j < 4; ++j) {
            int key = kbase + lg * 4 + j;
            bool ok = (key <= row) && (key > row - WIN);
            a[j] = ok ? a[j] : -1e30f;
            b[j] = ok ? b[j] : -1e30f;
          }
        }
        float e1[4], e2[4];
#pragma unroll
        for (int j = 0; j < 4; ++j) {
          e1[j] = __builtin_amdgcn_exp2f(a[j]);  // exp2(-1e30) flushes to 0
          e2[j] = __builtin_amdgcn_exp2f(b[j]);
          acc1 += e1[j];
          acc2 += e2[j];
        }
        u32 q0, q1, q2, q3;
        asm("v_cvt_pk_bf16_f32 %0, %1, %2" : "=v"(q0) : "v"(e1[0]), "v"(e1[1]));
        asm("v_cvt_pk_bf16_f32 %0, %1, %2" : "=v"(q1) : "v"(e1[2]), "v"(e1[3]));
        asm("v_cvt_pk_bf16_f32 %0, %1, %2" : "=v"(q2) : "v"(e2[0]), "v"(e2[1]));
        asm("v_cvt_pk_bf16_f32 %0, %1, %2" : "=v"(q3) : "v"(e2[2]), "v"(e2[3]));
        p[tc][kt * 2] = q0;
        p[tc][kt * 2 + 1] = q1;
        p[tc][8 + kt * 2] = q2;
        p[tc][8 + kt * 2 + 1] = q3;
      }
      z1 += acc1; z2 += acc2;
    }
  }

  // merge the 4 lg-group partials (lanes ll, ll+16, ll+32, ll+48 share q=ll)
  z1 += __shfl_xor(z1, 16, 64); z1 += __shfl_xor(z1, 32, 64);
  z2 += __shfl_xor(z2, 16, 64); z2 += __shfl_xor(z2, 32, 64);
  const float lm = lam[h];
  const float cfac = lm * z1 * __builtin_amdgcn_rcpf(z2);  // c = lm*z1/z2

  // ---- phase B: u = relu(e1 - c*e2), transpose, PV (V staged; no K/QK/exp) ----
  f32x4 o[8];
#pragma unroll
  for (int dt = 0; dt < 8; ++dt) o[dt] = zero;
  float dsum = 0.f;
  u16* Pw = &P[w][0];

  WAIT_VMCNT0;      // phase-A trailing stages landed
  __syncthreads();  // all waves done with phase-A buffers

  stageV(0, 0);
  stageV(1, (nch > 1) ? 1 : 0);

#pragma unroll
  for (int tc = 0; tc < 9; ++tc) {
    WAIT_VMCNT4;                    // own stage tc landed
    __builtin_amdgcn_s_barrier();   // all waves' stage tc landed
    {
      int ci = tc + 2; if (ci > nch - 1) ci = nch - 1;  // clamped, uniform
      stageV((tc + 2) % 3, ci);
    }
    if (tc < nch) {  // uniform
      const int c = kbeg + tc * 64;
      const u16* Vb = (const u16*)((const char*)KV + (size_t)(tc % 3) * 16384);
      __builtin_amdgcn_s_setprio(1);
#pragma unroll
      for (int kt = 0; kt < 4; ++kt) {
        const int kbase = c + kt * 16;
        if (kbase > qs + 15 || kbase + 15 < qs - (WIN - 1)) {  // same skip as phase A
          ushort4 zz; zz.x = zz.y = zz.z = zz.w = 0;
          *(ushort4*)(&Pw[ll * 72 + kt * 16 + lg * 4]) = zz;
          continue;
        }
        const u32 q0 = p[tc][kt * 2], q1 = p[tc][kt * 2 + 1];
        const u32 q2 = p[tc][8 + kt * 2], q3 = p[tc][8 + kt * 2 + 1];
        float u4[4];
        u4[0] = fmaxf(fmaf(-cfac, bflo(q2), bflo(q0)), 0.f);
        u4[1] = fmaxf(fmaf(-cfac, bfhi(q2), bfhi(q0)), 0.f);
        u4[2] = fmaxf(fmaf(-cfac, bflo(q3), bflo(q1)), 0.f);
        u4[3] = fmaxf(fmaf(-cfac, bfhi(q3), bfhi(q1)), 0.f);
        dsum += u4[0] + u4[1] + u4[2] + u4[3];
        u32 p01, p23;
        asm("v_cvt_pk_bf16_f32 %0, %1, %2" : "=v"(p01) : "v"(u4[0]), "v"(u4[1]));
        asm("v_cvt_pk_bf16_f32 %0, %1, %2" : "=v"(p23) : "v"(u4[2]), "v"(u4[3]));
        uint2 pk; pk.x = p01; pk.y = p23;
        *(uint2*)(&Pw[ll * 72 + kt * 16 + lg * 4]) = pk;
      }
      // per-wave LDS transpose round-trip (wave-synchronous; compiler waits lgkm)
      s16x8 pf0 = *(const s16x8*)(&Pw[ll * 72 + lg * 8]);
      s16x8 pf1 = *(const s16x8*)(&Pw[ll * 72 + 32 + lg * 8]);
#pragma unroll
      for (int dt = 0; dt < 8; ++dt) {
        const int d = dt * 16 + ll;
        const u32 sw = (u32)(d & 7);
        s16x8 vf0 = *(const s16x8*)(Vb + (size_t)d * 64 + ((lg ^ sw) * 8));
        s16x8 vf1 = *(const s16x8*)(Vb + (size_t)d * 64 + (((4 + lg) ^ sw) * 8));
        o[dt] = __builtin_amdgcn_mfma_f32_16x16x32_bf16(pf0, vf0, o[dt], 0, 0, 0);
        o[dt] = __builtin_amdgcn_mfma_f32_16x16x32_bf16(pf1, vf1, o[dt], 0, 0, 0);
      }
      __builtin_amdgcn_s_setprio(0);
    }
  }
  WAIT_VMCNT0;  // drain trailing stages before kernel end

  // dsum: merge lg partials; out = sum(u*v)/(sum(u) + z1*1e-6)
  dsum += __shfl_xor(dsum, 16, 64);
  dsum += __shfl_xor(dsum, 32, 64);
  const float rds = __builtin_amdgcn_rcpf(dsum + z1 * 1e-6f);
  float rdsj[4];
#pragma unroll
  for (int j = 0; j < 4; ++j) rdsj[j] = __shfl(rds, lg * 4 + j, 64);

#pragma unroll
  for (int dt = 0; dt < 8; ++dt) {
#pragma unroll
    for (int j = 0; j < 4; ++j) {
      int srow = qs + lg * 4 + j;
      ao[(size_t)srow * DMODEL + h * HD + dt * 16 + ll] = f2bf(o[dt][j] * rdsj[j]);
    }
  }
}

// ---------------- launch ----------------

extern "C" void kernel_launch(void* const* d_in, const int* in_sizes, int n_in,
                              void* d_out, int out_size, void* d_ws, size_t ws_size,
                              hipStream_t stream) {
  const float* x = (const float*)d_in[0];
  const float* Wq = (const float*)d_in[1];
  const float* Wk = (const float*)d_in[2];
  const float* Wv = (const float*)d_in[3];
  const float* Wo = (const float*)d_in[4];
  const float* lam = (const float*)d_in[5];
  float* out = (float*)d_out;

  char* ws = (char*)d_ws;
  u16* xb = (u16*)(ws);                               // 8 MB  [2048][2048]
  u16* WT = (u16*)(ws + (8u << 20));                  // 12 MB [3072][2048] (Wq^T|Wk^T|Wv^T)
  u16* WoT = (u16*)(ws + (20u << 20));                // 8 MB  [2048][2048]
  u16* qr = (u16*)(ws + (28u << 20));                 // 8 MB  [16][2048][128]
  u16* kr = (u16*)(ws + (36u << 20));                 // 2 MB  [4][2048][128]
  u16* vt = (u16*)(ws + (38u << 20));                 // 2 MB  [4][128][2048]
  u16* ao = (u16*)(ws + (40u << 20));                 // 8 MB  [2048][2048]
  float2* cs = (float2*)(ws + (48u << 20));           // 1 MB  [2048][64]

  k_prep<<<14848, 256, 0, stream>>>(x, xb, Wq, Wk, Wv, Wo, WT, WoT, cs);

  k_gemm<0><<<dim3(32, 24), 256, 0, stream>>>(xb, WT, nullptr, 2048, 3072, qr, kr, vt);

  // K roped in-place; Q-rope (+QSCALE, exp2-domain fold) fused into k_attn
  k_rope_k<<<(NKV * S_LEN * 64) / 256, 256, 0, stream>>>(kr, cs);

  k_attn<<<dim3(S_LEN / 16, NKV), 256, 0, stream>>>(qr, kr, vt, lam, cs, ao);

  k_gemm<1><<<dim3(32, 16), 256, 0, stream>>>(ao, WoT, out, 2048, 2048, nullptr, nullptr, nullptr);
}

// Round 15
// 101.432 us; speedup vs baseline: 1.3084x; 1.0325x over previous
//
#include <hip/hip_runtime.h>

typedef unsigned int u32;
typedef unsigned short u16;
typedef __attribute__((ext_vector_type(4))) float f32x4;
typedef __attribute__((ext_vector_type(8))) short s16x8;

#define S_LEN 2048
#define DMODEL 2048
#define NH 16
#define NKV 4
#define HD 128
#define WIN 512
// 0.125 (1/sqrt(64)) * log2(e): folds score scale + exp2-domain conversion into Q
#define QSCALE 0.18033688011112042f

#define WAIT_VMCNT4 asm volatile("s_waitcnt vmcnt(4)" ::: "memory")
#define WAIT_VMCNT0 asm volatile("s_waitcnt vmcnt(0)" ::: "memory")

__device__ __forceinline__ u16 f2bf(float f) {
  union { float f; u32 u; } v; v.f = f;
  u32 r = v.u + 0x7FFFu + ((v.u >> 16) & 1u);
  return (u16)(r >> 16);
}
__device__ __forceinline__ float bf2f(u16 h) {
  union { u32 u; float f; } v; v.u = ((u32)h) << 16;
  return v.f;
}
__device__ __forceinline__ float bflo(u32 p) {  // low bf16 of packed pair
  union { u32 u; float f; } v; v.u = p << 16;
  return v.f;
}
__device__ __forceinline__ float bfhi(u32 p) {  // high bf16 of packed pair
  union { u32 u; float f; } v; v.u = p & 0xFFFF0000u;
  return v.f;
}

__device__ __forceinline__ void async16(const void* g, void* l) {
  __builtin_amdgcn_global_load_lds((const __attribute__((address_space(1))) void*)g,
                                   (__attribute__((address_space(3))) void*)l, 16, 0, 0);
}

// ---------------- prep kernel ----------------
// bid < 4096: x f32->bf16 convert. 4096..14336: weight transposes
// (Wq 4096 | Wk 1024 | Wv 1024 | Wo 4096). >=14336: rope cos/sin table.
__global__ __launch_bounds__(256) void k_prep(const float* __restrict__ x, u16* __restrict__ xb,
                                              const float* __restrict__ Wq,
                                              const float* __restrict__ Wk,
                                              const float* __restrict__ Wv,
                                              const float* __restrict__ Wo,
                                              u16* __restrict__ WT, u16* __restrict__ WoT,
                                              float2* __restrict__ cs) {
  __shared__ float tile[32][33];
  const int bid = blockIdx.x;
  if (bid >= 14336) {  // rope table: 512 blocks x 4 s-rows x 64 d
    int s = (bid - 14336) * 4 + (threadIdx.x >> 6);
    int d = threadIdx.x & 63;
    float invf = expf(-((float)(2 * d) / (float)HD) * logf(10000.0f));
    float fr = (float)s * invf;
    float sv, cv;
    sincosf(fr, &sv, &cv);
    cs[s * 64 + d] = make_float2(cv, sv);
    return;
  }
  if (bid < 4096) {
    int i = bid * 256 + threadIdx.x;
    float4 v = ((const float4*)x)[i];
    ushort4 o;
    o.x = f2bf(v.x); o.y = f2bf(v.y); o.z = f2bf(v.z); o.w = f2bf(v.w);
    ((ushort4*)xb)[i] = o;
    return;
  }
  const int b = bid - 4096;
  const float* src;
  u16* dst;
  int N, nt, kt;
  if (b < 4096) {
    src = Wq; dst = WT; N = 2048; nt = b & 63; kt = b >> 6;
  } else if (b < 5120) {
    int i = b - 4096;
    src = Wk; dst = WT + (size_t)2048 * 2048; N = 512; nt = i & 15; kt = i >> 4;
  } else if (b < 6144) {
    int i = b - 5120;
    src = Wv; dst = WT + (size_t)2560 * 2048; N = 512; nt = i & 15; kt = i >> 4;
  } else {
    int i = b - 6144;
    src = Wo; dst = WoT; N = 2048; nt = i & 63; kt = i >> 6;
  }
  const int tx = threadIdx.x & 31, ty = threadIdx.x >> 5;
  const int n0 = nt * 32, k0 = kt * 32;
#pragma unroll
  for (int i = 0; i < 4; ++i)
    tile[ty + 8 * i][tx] = src[(size_t)(k0 + ty + 8 * i) * N + n0 + tx];
  __syncthreads();
#pragma unroll
  for (int i = 0; i < 4; ++i)
    dst[(size_t)(n0 + ty + 8 * i) * 2048 + k0 + tx] = f2bf(tile[tx][ty + 8 * i]);
}

// ---------------- GEMM (BK=64, 2-buf T3-min, 3 blocks/CU) ----------------
// A [M][K] bf16 row-major, BT [N][K] bf16. 64x128 tile, BK=64, 4 waves (2x2 of
// 32x64), double-buffered LDS (T3-min), chunked XCD swizzle.
// MODE 0: scatter epilogue -> qr[h][s][d], kr[h][s][d] (K-RoPE FUSED via LDS
//         pair-exchange: block n0 in [2048,2560) covers full d=0..127 for one
//         head; rope pairs (d, d+64) cross waves -> fp32 LDS round-trip),
//         vt[h][d][s].
// MODE 1: plain fp32 C[M][N]

template <int MODE>
__global__ __launch_bounds__(256) void k_gemm(const u16* __restrict__ A, const u16* __restrict__ BT,
                                              float* __restrict__ Cf, int K, int N,
                                              u16* __restrict__ qr, u16* __restrict__ kr,
                                              u16* __restrict__ vt,
                                              const float2* __restrict__ cs) {
  // A rows 0..63, B rows 64..191; each row 64 u16 = 128B; 24KB per buffer
  __shared__ u16 S[2][192 * 64];
  const int t = threadIdx.x;
  const int l = t & 63, w = t >> 6;
  const int lg = l >> 4, ll = l & 15;

  // chunked XCD swizzle (bijective: nwg % 8 == 0 for both call sites)
  const u32 nwg = gridDim.x * gridDim.y;
  const u32 bid = blockIdx.y * gridDim.x + blockIdx.x;  // m-fastest linearization
  const u32 sid = (bid & 7u) * (nwg >> 3) + (bid >> 3);
  const int m0 = (int)(sid % gridDim.x) * 64;
  const int n0 = (int)(sid / gridDim.x) * 128;

  const int wm = (w >> 1) * 32, wn = (w & 1) * 64;

  const u16* gp[6];
  u32 lo[6];
#pragma unroll
  for (int j = 0; j < 6; ++j) {
    u32 u = (u32)t * 16u + (u32)j * 4096u;
    u32 row = u >> 7;
    u32 slot = ((u >> 4) & 7u) ^ (row & 7u);
    lo[j] = u;
    gp[j] = (row < 64 ? A + (size_t)(m0 + (int)row) * K
                      : BT + (size_t)(n0 + (int)(row - 64)) * K) + slot * 8;
  }
  auto stage = [&](int b, int k0) {
#pragma unroll
    for (int j = 0; j < 6; ++j) async16(gp[j] + k0, (char*)S[b] + lo[j]);
  };

  f32x4 acc[2][4];
#pragma unroll
  for (int i = 0; i < 2; ++i)
#pragma unroll
    for (int j = 0; j < 4; ++j) acc[i][j] = (f32x4){0.f, 0.f, 0.f, 0.f};

  stage(0, 0);
  __syncthreads();

  const int nit = K / 64;
#pragma unroll 2
  for (int it = 0; it < nit; ++it) {
    const int cur = it & 1;
    if (it + 1 < nit) stage(cur ^ 1, (it + 1) * 64);  // loads fly under compute

    s16x8 af[2][2], bq[4][2];
#pragma unroll
    for (int mt = 0; mt < 2; ++mt) {
      u32 r = (u32)(wm + mt * 16 + ll);
#pragma unroll
      for (int ks = 0; ks < 2; ++ks)
        af[mt][ks] = *(const s16x8*)((const char*)S[cur] + r * 128u +
                                     ((((u32)(ks * 4 + lg)) ^ (r & 7u)) * 16u));
    }
#pragma unroll
    for (int nt = 0; nt < 4; ++nt) {
      u32 r = (u32)(64 + wn + nt * 16 + ll);
#pragma unroll
      for (int ks = 0; ks < 2; ++ks)
        bq[nt][ks] = *(const s16x8*)((const char*)S[cur] + r * 128u +
                                     ((((u32)(ks * 4 + lg)) ^ (r & 7u)) * 16u));
    }
#pragma unroll
    for (int ks = 0; ks < 2; ++ks)
#pragma unroll
      for (int mt = 0; mt < 2; ++mt)
#pragma unroll
        for (int nt = 0; nt < 4; ++nt)
          acc[mt][nt] = __builtin_amdgcn_mfma_f32_16x16x32_bf16(af[mt][ks], bq[nt][ks],
                                                                acc[mt][nt], 0, 0, 0);
    __syncthreads();
  }

  if (MODE == 1) {
#pragma unroll
    for (int mt = 0; mt < 2; ++mt) {
      int srow = m0 + wm + mt * 16 + lg * 4;
#pragma unroll
      for (int nt = 0; nt < 4; ++nt) {
        int col = n0 + wn + nt * 16 + ll;
        f32x4 a = acc[mt][nt];
#pragma unroll
        for (int j = 0; j < 4; ++j) Cf[(size_t)(srow + j) * N + col] = a[j];
      }
    }
  } else if (n0 >= 2048 && n0 < 2560) {
    // ---- K-projection block: fused RoPE epilogue ----
    // acc -> LDS fp32 [64][132] (pad keeps pair-reads 2-way/free), pair-rope
    // (d, d+64) from cs, coalesced bf16 writes to kr. Last K-iter ended with
    // __syncthreads so S is free to reuse (33KB <= 48KB).
    float* Lf = (float*)&S[0][0];
#pragma unroll
    for (int nt = 0; nt < 4; ++nt) {
      int ccol = wn + nt * 16 + ll;
#pragma unroll
      for (int mt = 0; mt < 2; ++mt) {
        int rrow = wm + mt * 16 + lg * 4;
        f32x4 a = acc[mt][nt];
#pragma unroll
        for (int j = 0; j < 4; ++j) Lf[(rrow + j) * 132 + ccol] = a[j];
      }
    }
    __syncthreads();
    const int hh = (n0 - 2048) >> 7;
#pragma unroll
    for (int it2 = 0; it2 < 16; ++it2) {
      const int rrow = it2 * 4 + w;   // each wave handles one row per iter
      const int c = l;                // 0..63
      float a = Lf[rrow * 132 + c];
      float b = Lf[rrow * 132 + c + 64];
      const int s = m0 + rrow;
      float2 cv = cs[(size_t)s * 64 + c];
      u16* p = kr + ((size_t)hh * S_LEN + s) * HD;
      p[c]      = f2bf(a * cv.x - b * cv.y);
      p[c + 64] = f2bf(b * cv.x + a * cv.y);
    }
  } else {
#pragma unroll
    for (int nt = 0; nt < 4; ++nt) {
      int cb = n0 + wn + nt * 16;  // wave-uniform
#pragma unroll
      for (int mt = 0; mt < 2; ++mt) {
        int srow = m0 + wm + mt * 16 + lg * 4;
        f32x4 a = acc[mt][nt];
        if (cb < 2048) {
          int hh = cb >> 7, d = (cb & 127) + ll;
          u16* p = qr + ((size_t)hh * S_LEN) * HD + d;
#pragma unroll
          for (int j = 0; j < 4; ++j) p[(size_t)(srow + j) * HD] = f2bf(a[j]);
        } else {
          int hh = (cb - 2560) >> 7, d = ((cb - 2560) & 127) + ll;
          ushort4 pk;
          pk.x = f2bf(a[0]); pk.y = f2bf(a[1]); pk.z = f2bf(a[2]); pk.w = f2bf(a[3]);
          *(ushort4*)(vt + ((size_t)hh * HD + d) * S_LEN + srow) = pk;
        }
      }
    }
  }
}

// ---------------- attention ----------------
// Single-QK^T formulation: d = relu(a1 - lm*a2) = relu(e1 - c*e2)/z1 with
// c = lm*z1/z2 and e = exp2(score) UNNORMALIZED, so pass 2 needs no K, no
// QK^T MFMA, and no exp -- phase A caches packed-bf16 e1,e2 in REGISTERS
// (p[9][16] = 144 VGPRs; free because the grid caps occupancy at 2 waves/SIMD
// anyway). Output: out = sum(u*v) / (sum(u) + z1*1e-6), u = relu(e1 - c*e2).
// Head-sharing grid (S/16, NKV), wave w = head hkv*4+w. Both phases: fixed 9
// unrolled 64-key chunks (static p indexing), uniform guards, 3-buffer
// counted-vmcnt pipeline (2-ahead, clamped tail stages).
// Phase A: K tiles (64 rows x 256B, XOR-swz). Phase B: V tiles ([d=128][k=64]
// 128B rows, XOR-swz) reusing the same buffers. Q-RoPE in-register.
__global__ __launch_bounds__(256, 2) void k_attn(const u16* __restrict__ qr,
                                                 const u16* __restrict__ kr,
                                                 const u16* __restrict__ vt,
                                                 const float* __restrict__ lam,
                                                 const float2* __restrict__ cs,
                                                 u16* __restrict__ ao) {
  __shared__ u16 KV[3][8192];   // 3 x 16KB: phase A = K bufs, phase B = V bufs
  __shared__ u16 P[4][16 * 72]; // per-wave u^T transpose tile (16 q x 64 keys)
  const int t = threadIdx.x;
  const int l = t & 63, w = t >> 6;
  const int lg = l >> 4, ll = l & 15;
  const int hkv = blockIdx.y;
  const int h = hkv * 4 + w;        // this wave's head
  const int qs = blockIdx.x * 16;   // block-shared q range [qs, qs+16)
  const int row = qs + ll;          // this lane's q row

  const u16* Qp = qr + ((size_t)h * S_LEN + qs) * HD;
  const u16* Kp = kr + (size_t)hkv * S_LEN * HD;
  const u16* Vp = vt + (size_t)hkv * HD * S_LEN;

  const int kbeg = (qs >= 512) ? ((qs - 511) & ~63) : 0;
  const int nch = (qs + 15 - kbeg) / 64 + 1;  // 1..9 64-key chunks

  // K staging coords (16KB tile: 64 rows x 256B, 16 slots, slot ^= row&7)
  u32 ku1[4], kr1[4], ks1[4];
#pragma unroll
  for (int j = 0; j < 4; ++j) {
    u32 u = (u32)t * 16u + (u32)j * 4096u;
    ku1[j] = u;
    kr1[j] = u >> 8;
    ks1[j] = ((u >> 4) & 15u) ^ (kr1[j] & 7u);
  }
  // V staging coords (16KB tile: 128 d-rows x 128B, 8 slots, slot ^= d&7)
  u32 vu[4], vdr[4], vsl[4];
#pragma unroll
  for (int j = 0; j < 4; ++j) {
    u32 u = (u32)t * 16u + (u32)j * 4096u;
    vu[j] = u;
    vdr[j] = u >> 7;
    vsl[j] = ((u >> 4) & 7u) ^ (vdr[j] & 7u);
  }

  auto stageK = [&](int buf, int tcc) {
    const int c = kbeg + tcc * 64;
    char* dst = (char*)KV + (size_t)buf * 16384;
#pragma unroll
    for (int j = 0; j < 4; ++j)
      async16(Kp + (size_t)(c + kr1[j]) * HD + ks1[j] * 8, dst + ku1[j]);
  };
  auto stageV = [&](int buf, int tcc) {
    const int c = kbeg + tcc * 64;
    char* dst = (char*)KV + (size_t)buf * 16384;
#pragma unroll
    for (int j = 0; j < 4; ++j)
      async16(Vp + (size_t)vdr[j] * S_LEN + c + vsl[j] * 8, dst + vu[j]);
  };

  // ---- Q fragments + in-register RoPE (+QSCALE) ----
  s16x8 qa[4];
#pragma unroll
  for (int i = 0; i < 4; ++i)
    qa[i] = *(const s16x8*)(Qp + (size_t)ll * HD + i * 32 + lg * 8);
  {
    const float4* cp4 = (const float4*)(cs + (size_t)row * 64);  // 32 float4/row
#pragma unroll
    for (int i = 0; i < 2; ++i) {
      float4 cv[4];
#pragma unroll
      for (int jj = 0; jj < 4; ++jj) cv[jj] = cp4[i * 16 + lg * 4 + jj];
      s16x8 lo = qa[i], hi = qa[i + 2];
#pragma unroll
      for (int j = 0; j < 8; ++j) {
        float cc = (j & 1) ? cv[j >> 1].z : cv[j >> 1].x;
        float ss = (j & 1) ? cv[j >> 1].w : cv[j >> 1].y;
        float a = bf2f((u16)lo[j]), b = bf2f((u16)hi[j]);
        lo[j] = (short)f2bf((a * cc - b * ss) * QSCALE);
        hi[j] = (short)f2bf((b * cc + a * ss) * QSCALE);
      }
      qa[i] = lo; qa[i + 2] = hi;
    }
  }

  const f32x4 zero = {0.f, 0.f, 0.f, 0.f};
  float z1 = 0.f, z2 = 0.f;
  u32 p[9][16];  // packed bf16: [tc][0..7]=e1 pairs, [tc][8..15]=e2 pairs

  // ---- phase A: QK^T + exp2, cache e's in regs, accumulate z ----
  stageK(0, 0);
  stageK(1, (nch > 1) ? 1 : 0);

#pragma unroll
  for (int tc = 0; tc < 9; ++tc) {
    WAIT_VMCNT4;                    // own stage tc landed (in-order vmem)
    __builtin_amdgcn_s_barrier();   // all waves' stage tc landed
    {
      int ci = tc + 2; if (ci > nch - 1) ci = nch - 1;  // clamped, uniform
      stageK((tc + 2) % 3, ci);
    }
    if (tc < nch) {  // uniform within block
      const int c = kbeg + tc * 64;
      const u16* Kb = (const u16*)((const char*)KV + (size_t)(tc % 3) * 16384);
      float acc1 = 0.f, acc2 = 0.f;
#pragma unroll
      for (int kt = 0; kt < 4; ++kt) {
        const int kbase = c + kt * 16;
        if (kbase > qs + 15 || kbase + 15 < qs - (WIN - 1)) continue;  // uniform; phase B skips same
        const int kr_ = kt * 16 + ll;
        const u16* kp = Kb + kr_ * 128;
        const u32 sw = (u32)(kr_ & 7);
        s16x8 b0 = *(const s16x8*)(kp + ((lg ^ sw) * 8));
        s16x8 b1 = *(const s16x8*)(kp + (((4 + lg) ^ sw) * 8));
        s16x8 b2 = *(const s16x8*)(kp + (((8 + lg) ^ sw) * 8));
        s16x8 b3 = *(const s16x8*)(kp + (((12 + lg) ^ sw) * 8));
        f32x4 a = __builtin_amdgcn_mfma_f32_16x16x32_bf16(b0, qa[0], zero, 0, 0, 0);
        a = __builtin_amdgcn_mfma_f32_16x16x32_bf16(b1, qa[1], a, 0, 0, 0);
        f32x4 b = __builtin_amdgcn_mfma_f32_16x16x32_bf16(b2, qa[2], zero, 0, 0, 0);
        b = __builtin_amdgcn_mfma_f32_16x16x32_bf16(b3, qa[3], b, 0, 0, 0);
        const bool fullk = (kbase + 15 <= qs) && (kbase >= qs - 496);
        if (!fullk) {
#pragma unroll
          for (int j = 0; j < 4; ++j) {
            int key = kbase + lg * 4 + j;
            bool ok = (key <= row) && (key > row - WIN);
            a[j] = ok ? a[j] : -1e30f;
            b[j] = ok ? b[j] : -1e30f;
          }
        }
        float e1[4], e2[4];
#pragma unroll
        for (int j = 0; j < 4; ++j) {
          e1[j] = __builtin_amdgcn_exp2f(a[j]);  // exp2(-1e30) flushes to 0
          e2[j] = __builtin_amdgcn_exp2f(b[j]);
          acc1 += e1[j];
          acc2 += e2[j];
        }
        u32 q0, q1, q2, q3;
        asm("v_cvt_pk_bf16_f32 %0, %1, %2" : "=v"(q0) : "v"(e1[0]), "v"(e1[1]));
        asm("v_cvt_pk_bf16_f32 %0, %1, %2" : "=v"(q1) : "v"(e1[2]), "v"(e1[3]));
        asm("v_cvt_pk_bf16_f32 %0, %1, %2" : "=v"(q2) : "v"(e2[0]), "v"(e2[1]));
        asm("v_cvt_pk_bf16_f32 %0, %1, %2" : "=v"(q3) : "v"(e2[2]), "v"(e2[3]));
        p[tc][kt * 2] = q0;
        p[tc][kt * 2 + 1] = q1;
        p[tc][8 + kt * 2] = q2;
        p[tc][8 + kt * 2 + 1] = q3;
      }
      z1 += acc1; z2 += acc2;
    }
  }

  // merge the 4 lg-group partials (lanes ll, ll+16, ll+32, ll+48 share q=ll)
  z1 += __shfl_xor(z1, 16, 64); z1 += __shfl_xor(z1, 32, 64);
  z2 += __shfl_xor(z2, 16, 64); z2 += __shfl_xor(z2, 32, 64);
  const float lm = lam[h];
  const float cfac = lm * z1 * __builtin_amdgcn_rcpf(z2);  // c = lm*z1/z2

  // ---- phase B: u = relu(e1 - c*e2), transpose, PV (V staged; no K/QK/exp) ----
  f32x4 o[8];
#pragma unroll
  for (int dt = 0; dt < 8; ++dt) o[dt] = zero;
  float dsum = 0.f;
  u16* Pw = &P[w][0];

  WAIT_VMCNT0;      // phase-A trailing stages landed
  __syncthreads();  // all waves done with phase-A buffers

  stageV(0, 0);
  stageV(1, (nch > 1) ? 1 : 0);

#pragma unroll
  for (int tc = 0; tc < 9; ++tc) {
    WAIT_VMCNT4;                    // own stage tc landed
    __builtin_amdgcn_s_barrier();   // all waves' stage tc landed
    {
      int ci = tc + 2; if (ci > nch - 1) ci = nch - 1;  // clamped, uniform
      stageV((tc + 2) % 3, ci);
    }
    if (tc < nch) {  // uniform
      const int c = kbeg + tc * 64;
      const u16* Vb = (const u16*)((const char*)KV + (size_t)(tc % 3) * 16384);
      __builtin_amdgcn_s_setprio(1);
#pragma unroll
      for (int kt = 0; kt < 4; ++kt) {
        const int kbase = c + kt * 16;
        if (kbase > qs + 15 || kbase + 15 < qs - (WIN - 1)) {  // same skip as phase A
          ushort4 zz; zz.x = zz.y = zz.z = zz.w = 0;
          *(ushort4*)(&Pw[ll * 72 + kt * 16 + lg * 4]) = zz;
          continue;
        }
        const u32 q0 = p[tc][kt * 2], q1 = p[tc][kt * 2 + 1];
        const u32 q2 = p[tc][8 + kt * 2], q3 = p[tc][8 + kt * 2 + 1];
        float u4[4];
        u4[0] = fmaxf(fmaf(-cfac, bflo(q2), bflo(q0)), 0.f);
        u4[1] = fmaxf(fmaf(-cfac, bfhi(q2), bfhi(q0)), 0.f);
        u4[2] = fmaxf(fmaf(-cfac, bflo(q3), bflo(q1)), 0.f);
        u4[3] = fmaxf(fmaf(-cfac, bfhi(q3), bfhi(q1)), 0.f);
        dsum += u4[0] + u4[1] + u4[2] + u4[3];
        u32 p01, p23;
        asm("v_cvt_pk_bf16_f32 %0, %1, %2" : "=v"(p01) : "v"(u4[0]), "v"(u4[1]));
        asm("v_cvt_pk_bf16_f32 %0, %1, %2" : "=v"(p23) : "v"(u4[2]), "v"(u4[3]));
        uint2 pk; pk.x = p01; pk.y = p23;
        *(uint2*)(&Pw[ll * 72 + kt * 16 + lg * 4]) = pk;
      }
      // per-wave LDS transpose round-trip (wave-synchronous; compiler waits lgkm)
      s16x8 pf0 = *(const s16x8*)(&Pw[ll * 72 + lg * 8]);
      s16x8 pf1 = *(const s16x8*)(&Pw[ll * 72 + 32 + lg * 8]);
#pragma unroll
      for (int dt = 0; dt < 8; ++dt) {
        const int d = dt * 16 + ll;
        const u32 sw = (u32)(d & 7);
        s16x8 vf0 = *(const s16x8*)(Vb + (size_t)d * 64 + ((lg ^ sw) * 8));
        s16x8 vf1 = *(const s16x8*)(Vb + (size_t)d * 64 + (((4 + lg) ^ sw) * 8));
        o[dt] = __builtin_amdgcn_mfma_f32_16x16x32_bf16(pf0, vf0, o[dt], 0, 0, 0);
        o[dt] = __builtin_amdgcn_mfma_f32_16x16x32_bf16(pf1, vf1, o[dt], 0, 0, 0);
      }
      __builtin_amdgcn_s_setprio(0);
    }
  }
  WAIT_VMCNT0;  // drain trailing stages before kernel end

  // dsum: merge lg partials; out = sum(u*v)/(sum(u) + z1*1e-6)
  dsum += __shfl_xor(dsum, 16, 64);
  dsum += __shfl_xor(dsum, 32, 64);
  const float rds = __builtin_amdgcn_rcpf(dsum + z1 * 1e-6f);
  float rdsj[4];
#pragma unroll
  for (int j = 0; j < 4; ++j) rdsj[j] = __shfl(rds, lg * 4 + j, 64);

#pragma unroll
  for (int dt = 0; dt < 8; ++dt) {
#pragma unroll
    for (int j = 0; j < 4; ++j) {
      int srow = qs + lg * 4 + j;
      ao[(size_t)srow * DMODEL + h * HD + dt * 16 + ll] = f2bf(o[dt][j] * rdsj[j]);
    }
  }
}

// ---------------- launch ----------------

extern "C" void kernel_launch(void* const* d_in, const int* in_sizes, int n_in,
                              void* d_out, int out_size, void* d_ws, size_t ws_size,
                              hipStream_t stream) {
  const float* x = (const float*)d_in[0];
  const float* Wq = (const float*)d_in[1];
  const float* Wk = (const float*)d_in[2];
  const float* Wv = (const float*)d_in[3];
  const float* Wo = (const float*)d_in[4];
  const float* lam = (const float*)d_in[5];
  float* out = (float*)d_out;

  char* ws = (char*)d_ws;
  u16* xb = (u16*)(ws);                               // 8 MB  [2048][2048]
  u16* WT = (u16*)(ws + (8u << 20));                  // 12 MB [3072][2048] (Wq^T|Wk^T|Wv^T)
  u16* WoT = (u16*)(ws + (20u << 20));                // 8 MB  [2048][2048]
  u16* qr = (u16*)(ws + (28u << 20));                 // 8 MB  [16][2048][128]
  u16* kr = (u16*)(ws + (36u << 20));                 // 2 MB  [4][2048][128]
  u16* vt = (u16*)(ws + (38u << 20));                 // 2 MB  [4][128][2048]
  u16* ao = (u16*)(ws + (40u << 20));                 // 8 MB  [2048][2048]
  float2* cs = (float2*)(ws + (48u << 20));           // 1 MB  [2048][64]

  k_prep<<<14848, 256, 0, stream>>>(x, xb, Wq, Wk, Wv, Wo, WT, WoT, cs);

  // K-RoPE fused into the kr-block epilogue (cs ready from k_prep)
  k_gemm<0><<<dim3(32, 24), 256, 0, stream>>>(xb, WT, nullptr, 2048, 3072, qr, kr, vt, cs);

  k_attn<<<dim3(S_LEN / 16, NKV), 256, 0, stream>>>(qr, kr, vt, lam, cs, ao);

  k_gemm<1><<<dim3(32, 16), 256, 0, stream>>>(ao, WoT, out, 2048, 2048, nullptr, nullptr, nullptr, nullptr);
}